// Round 6
// baseline (507.977 us; speedup 1.0000x reference)
//
#include <hip/hip_runtime.h>
#include <math.h>

#define D_MODEL 1024
#define T_SEQ   1024
#define BATCH   4
#define NHEAD   16
#define HDIM    64

// keep counts: trunc(linspace(0.35,0.15,16)*64), min 1
__constant__ int KEEPC[16] = {22,21,20,19,18,18,17,16,15,14,13,13,12,11,10,9};

typedef short bh8  __attribute__((ext_vector_type(8)));
typedef float f32x4 __attribute__((ext_vector_type(4)));
typedef int   i32x4 __attribute__((ext_vector_type(4)));

__device__ __forceinline__ unsigned short f2bf(float f) {
    unsigned int u = __float_as_uint(f);
    return (unsigned short)((u + 0x7FFFu + ((u >> 16) & 1u)) >> 16);
}
__device__ __forceinline__ float bf2f(unsigned short h) {
    return __uint_as_float(((unsigned int)h) << 16);
}

// ---------------------------------------------------------------------------
// Cast weights once: kw -> (hi,lo) bf16 split; vw, ow -> single bf16.
// ---------------------------------------------------------------------------
__global__ void cast_weights(const float* __restrict__ kw,
                             unsigned short* __restrict__ kwh,
                             unsigned short* __restrict__ kwl,
                             const float* __restrict__ vw,
                             unsigned short* __restrict__ vwb,
                             const float* __restrict__ ow,
                             unsigned short* __restrict__ owb)
{
    const int NS = (D_MODEL * D_MODEL) / 8;
    int i = blockIdx.x * 256 + threadIdx.x;
    const float* src; unsigned short* dh; unsigned short* dl = nullptr;
    long off;
    if (i < NS)           { src = kw; dh = kwh; dl = kwl; off = i; }
    else if (i < 2 * NS)  { src = vw; dh = vwb; off = i - NS; }
    else if (i < 3 * NS)  { src = ow; dh = owb; off = i - 2 * NS; }
    else return;
    long e = off * 8;
    alignas(16) float fl[8];
    *(float4*)&fl[0] = *(const float4*)(src + e);
    *(float4*)&fl[4] = *(const float4*)(src + e + 4);
    uint4 hp, lp;
    unsigned int* hpw = (unsigned int*)&hp;
    unsigned int* lpw = (unsigned int*)&lp;
    #pragma unroll
    for (int c = 0; c < 4; c++) {
        unsigned short h0 = f2bf(fl[2 * c]), h1 = f2bf(fl[2 * c + 1]);
        hpw[c] = (unsigned int)h0 | ((unsigned int)h1 << 16);
        if (dl) {
            unsigned short l0 = f2bf(fl[2 * c] - bf2f(h0));
            unsigned short l1 = f2bf(fl[2 * c + 1] - bf2f(h1));
            lpw[c] = (unsigned int)l0 | ((unsigned int)l1 << 16);
        }
    }
    *(uint4*)(dh + e) = hp;
    if (dl) *(uint4*)(dl + e) = lp;
}

// ---------------------------------------------------------------------------
// prep_q: x -> 4 signed base-256 digit planes of n = rint(x * 2^23)
// (exact), and qw -> sign int8.
// ---------------------------------------------------------------------------
__global__ void prep_q(const float* __restrict__ x, signed char* __restrict__ dig,
                       const float* __restrict__ qw, signed char* __restrict__ sg)
{
    const int NX = (BATCH * T_SEQ * D_MODEL) / 8;   // 524288
    const int NW = (D_MODEL * D_MODEL) / 8;         // 131072
    const long PL = (long)BATCH * T_SEQ * D_MODEL;  // plane stride 4194304
    int i = blockIdx.x * 256 + threadIdx.x;
    if (i < NX) {
        long e = (long)i * 8;
        alignas(16) float f[8];
        *(float4*)&f[0] = *(const float4*)(x + e);
        *(float4*)&f[4] = *(const float4*)(x + e + 4);
        signed char d[4][8];
        #pragma unroll
        for (int c = 0; c < 8; c++) {
            int n = (int)rintf(f[c] * 8388608.0f);
            int d0 = (signed char)(n & 0xff); n = (n - d0) >> 8;
            int d1 = (signed char)(n & 0xff); n = (n - d1) >> 8;
            int d2 = (signed char)(n & 0xff); n = (n - d2) >> 8;
            d[0][c] = (signed char)d0; d[1][c] = (signed char)d1;
            d[2][c] = (signed char)d2; d[3][c] = (signed char)n;
        }
        #pragma unroll
        for (int p = 0; p < 4; p++)
            *(uint2*)(dig + p * PL + e) = *(uint2*)&d[p][0];
    } else if (i < NX + NW) {
        long e = (long)(i - NX) * 8;
        alignas(16) float f[8];
        *(float4*)&f[0] = *(const float4*)(qw + e);
        *(float4*)&f[4] = *(const float4*)(qw + e + 4);
        signed char s[8];
        #pragma unroll
        for (int c = 0; c < 8; c++)
            s[c] = (signed char)((f[c] > 0.f) - (f[c] < 0.f));
        *(uint2*)(sg + e) = *(uint2*)&s[0];
    }
}

// ---------------------------------------------------------------------------
// Q projection via EXACT int8 MFMA: q = 2^-23 * sum_p 256^p (Dp @ S^T) + b.
// Output fp32 HEAD-MAJOR: [(b*16+h)*1024 + t][d].
// ---------------------------------------------------------------------------
#define QST 80

__global__ __launch_bounds__(256, 2) void gemm_q_i8(
    const signed char* __restrict__ dig, const signed char* __restrict__ sg,
    const float* __restrict__ Bi, float* __restrict__ Y)
{
    __shared__ signed char Ad[4][64 * QST];
    __shared__ signed char Bs[64 * QST];

    const long PL = (long)BATCH * T_SEQ * D_MODEL;
    int tid  = threadIdx.x;
    int bm   = blockIdx.y * 64, bn = blockIdx.x * 64;
    int wave = tid >> 6, lane = tid & 63;
    int l15  = lane & 15, rg = lane >> 4;
    int wm   = (wave >> 1) * 32, wn = (wave & 1) * 32;
    int srow = tid >> 2;
    int skof = (tid & 3) * 16;

    i32x4 acc[4][2][2];
    #pragma unroll
    for (int p = 0; p < 4; p++)
        #pragma unroll
        for (int i = 0; i < 2; i++)
            #pragma unroll
            for (int j = 0; j < 2; j++) acc[p][i][j] = (i32x4)0;

    const signed char* ap = dig + (size_t)(bm + srow) * D_MODEL + skof;
    const signed char* bp = sg + (size_t)(bn + srow) * D_MODEL + skof;

    for (int k0 = 0; k0 < D_MODEL; k0 += 64) {
        uint4 av[4], bv;
        #pragma unroll
        for (int p = 0; p < 4; p++) av[p] = *(const uint4*)(ap + p * PL);
        bv = *(const uint4*)(bp);
        ap += 64; bp += 64;

        __syncthreads();
        #pragma unroll
        for (int p = 0; p < 4; p++)
            *(uint4*)&Ad[p][srow * QST + skof] = av[p];
        *(uint4*)&Bs[srow * QST + skof] = bv;
        __syncthreads();

        i32x4 bf[2];
        #pragma unroll
        for (int j = 0; j < 2; j++)
            bf[j] = *(i32x4*)&Bs[(wn + j * 16 + l15) * QST + rg * 16];
        #pragma unroll
        for (int p = 0; p < 4; p++) {
            i32x4 af[2];
            #pragma unroll
            for (int i = 0; i < 2; i++)
                af[i] = *(i32x4*)&Ad[p][(wm + i * 16 + l15) * QST + rg * 16];
            #pragma unroll
            for (int i = 0; i < 2; i++)
                #pragma unroll
                for (int j = 0; j < 2; j++)
                    acc[p][i][j] = __builtin_amdgcn_mfma_i32_16x16x64_i8(
                        af[i], bf[j], acc[p][i][j], 0, 0, 0);
        }
    }

    int hh = bn >> 6;
    #pragma unroll
    for (int j = 0; j < 2; j++) {
        int col = bn + wn + j * 16 + l15;
        int dd = col & 63;
        float bvv = Bi[col];
        #pragma unroll
        for (int i = 0; i < 2; i++) {
            #pragma unroll
            for (int r = 0; r < 4; r++) {
                int row = bm + wm + i * 16 + rg * 4 + r;
                int bb = row >> 10, tt = row & 1023;
                long t = (long)acc[0][i][j][r]
                       + ((long)acc[1][i][j][r] << 8)
                       + ((long)acc[2][i][j][r] << 16)
                       + ((long)acc[3][i][j][r] << 24);
                float o = (float)((double)t * (1.0 / 8388608.0)) + bvv;
                Y[(((size_t)(bb * NHEAD + hh)) * T_SEQ + tt) * HDIM + dd] = o;
            }
        }
    }
}

// ---------------------------------------------------------------------------
// MFMA GEMM, bf16 split of fp32 A on the fly.
// split=1 (k-proj): 3-pass hi/lo product, fp32 out HEAD-MAJOR into Yf.
// split=0 (v-proj): single bf16 pass, bf16 out TRANSPOSED head-major Yv.
// ---------------------------------------------------------------------------
#define GLDK 72

__global__ __launch_bounds__(256, 2) void gemm_xsplit(
    const float* __restrict__ A, const unsigned short* __restrict__ Wh,
    const unsigned short* __restrict__ Wl, const float* __restrict__ Bi,
    float* __restrict__ Yf, unsigned short* __restrict__ Yv, int split)
{
    __shared__ unsigned short Ah[128 * GLDK];
    __shared__ unsigned short Al[128 * GLDK];
    __shared__ unsigned short Whs[128 * GLDK];
    __shared__ unsigned short Wls[128 * GLDK];

    int tid  = threadIdx.x;
    int bm   = blockIdx.y * 128, bn = blockIdx.x * 128;
    int wave = tid >> 6, lane = tid & 63;
    int l15  = lane & 15, q4 = lane >> 4;
    int wm   = (wave >> 1) * 64, wn = (wave & 1) * 64;
    int srow = tid >> 1;
    int scol = (tid & 1) * 32;

    f32x4 acc[4][4];
    #pragma unroll
    for (int i = 0; i < 4; i++)
        #pragma unroll
        for (int j = 0; j < 4; j++) acc[i][j] = (f32x4)0.f;

    const float* ap = A + (size_t)(bm + srow) * D_MODEL + scol;
    const unsigned short* whp = Wh + (size_t)(bn + srow) * D_MODEL + scol;
    const unsigned short* wlp = (split ? Wl : Wh) + (size_t)(bn + srow) * D_MODEL + scol;

    for (int k0 = 0; k0 < D_MODEL; k0 += 64) {
        alignas(16) float fl[32];
        #pragma unroll
        for (int c = 0; c < 8; c++) *(float4*)&fl[4 * c] = *(const float4*)(ap + 4 * c);
        uint4 w0 = *(const uint4*)(whp + 0),  w1 = *(const uint4*)(whp + 8);
        uint4 w2 = *(const uint4*)(whp + 16), w3 = *(const uint4*)(whp + 24);
        uint4 x0, x1, x2, x3;
        if (split) {
            x0 = *(const uint4*)(wlp + 0);  x1 = *(const uint4*)(wlp + 8);
            x2 = *(const uint4*)(wlp + 16); x3 = *(const uint4*)(wlp + 24);
        }
        ap += 64; whp += 64; wlp += 64;

        unsigned int hw[16], lw[16];
        #pragma unroll
        for (int c = 0; c < 16; c++) {
            unsigned short h0 = f2bf(fl[2 * c]), h1 = f2bf(fl[2 * c + 1]);
            hw[c] = (unsigned int)h0 | ((unsigned int)h1 << 16);
            if (split) {
                unsigned short l0 = f2bf(fl[2 * c] - bf2f(h0));
                unsigned short l1 = f2bf(fl[2 * c + 1] - bf2f(h1));
                lw[c] = (unsigned int)l0 | ((unsigned int)l1 << 16);
            }
        }

        __syncthreads();
        unsigned int* ah = (unsigned int*)&Ah[srow * GLDK + scol];
        #pragma unroll
        for (int g = 0; g < 4; g++)
            *(uint4*)(ah + 4 * g) = make_uint4(hw[4 * g], hw[4 * g + 1], hw[4 * g + 2], hw[4 * g + 3]);
        if (split) {
            unsigned int* al = (unsigned int*)&Al[srow * GLDK + scol];
            #pragma unroll
            for (int g = 0; g < 4; g++)
                *(uint4*)(al + 4 * g) = make_uint4(lw[4 * g], lw[4 * g + 1], lw[4 * g + 2], lw[4 * g + 3]);
        }
        unsigned short* ws = &Whs[srow * GLDK + scol];
        *(uint4*)(ws + 0) = w0; *(uint4*)(ws + 8)  = w1;
        *(uint4*)(ws + 16) = w2; *(uint4*)(ws + 24) = w3;
        if (split) {
            unsigned short* wl2 = &Wls[srow * GLDK + scol];
            *(uint4*)(wl2 + 0) = x0; *(uint4*)(wl2 + 8)  = x1;
            *(uint4*)(wl2 + 16) = x2; *(uint4*)(wl2 + 24) = x3;
        }
        __syncthreads();

        #pragma unroll
        for (int kc = 0; kc < 64; kc += 32) {
            bh8 ahf[4], whf[4];
            #pragma unroll
            for (int i = 0; i < 4; i++)
                ahf[i] = *(bh8*)&Ah[(wm + i * 16 + l15) * GLDK + kc + q4 * 8];
            #pragma unroll
            for (int j = 0; j < 4; j++)
                whf[j] = *(bh8*)&Whs[(wn + j * 16 + l15) * GLDK + kc + q4 * 8];
            #pragma unroll
            for (int i = 0; i < 4; i++)
                #pragma unroll
                for (int j = 0; j < 4; j++)
                    acc[i][j] = __builtin_amdgcn_mfma_f32_16x16x32_bf16(ahf[i], whf[j], acc[i][j], 0, 0, 0);
            if (split) {
                bh8 alf[4], wlf[4];
                #pragma unroll
                for (int i = 0; i < 4; i++)
                    alf[i] = *(bh8*)&Al[(wm + i * 16 + l15) * GLDK + kc + q4 * 8];
                #pragma unroll
                for (int j = 0; j < 4; j++)
                    wlf[j] = *(bh8*)&Wls[(wn + j * 16 + l15) * GLDK + kc + q4 * 8];
                #pragma unroll
                for (int i = 0; i < 4; i++)
                    #pragma unroll
                    for (int j = 0; j < 4; j++) {
                        acc[i][j] = __builtin_amdgcn_mfma_f32_16x16x32_bf16(ahf[i], wlf[j], acc[i][j], 0, 0, 0);
                        acc[i][j] = __builtin_amdgcn_mfma_f32_16x16x32_bf16(alf[i], whf[j], acc[i][j], 0, 0, 0);
                    }
            }
        }
    }

    #pragma unroll
    for (int j = 0; j < 4; j++) {
        int col = bn + wn + j * 16 + l15;
        int hh = col >> 6, dd = col & 63;
        float bv = Bi[col];
        #pragma unroll
        for (int i = 0; i < 4; i++) {
            int row0 = bm + wm + i * 16 + q4 * 4;
            int bb = row0 >> 10, tt = row0 & 1023;
            if (split) {
                float* yp = Yf + (((size_t)(bb * NHEAD + hh)) * T_SEQ + tt) * HDIM + dd;
                #pragma unroll
                for (int r = 0; r < 4; r++)
                    yp[(size_t)r * HDIM] = acc[i][j][r] + bv;
            } else {
                uint2 u;
                u.x = (unsigned int)f2bf(acc[i][j][0] + bv) | ((unsigned int)f2bf(acc[i][j][1] + bv) << 16);
                u.y = (unsigned int)f2bf(acc[i][j][2] + bv) | ((unsigned int)f2bf(acc[i][j][3] + bv) << 16);
                *(uint2*)(Yv + ((size_t)(bb * NHEAD + hh) * HDIM + dd) * T_SEQ + tt) = u;
            }
        }
    }
}

// ---------------------------------------------------------------------------
// Out-projection: bf16 ctx (model-major) @ bf16 W^T + bias, head mask on A.
// ---------------------------------------------------------------------------
__global__ __launch_bounds__(256, 2) void gemm_obf(
    const unsigned short* __restrict__ A, const unsigned short* __restrict__ W,
    const float* __restrict__ Bi, float* __restrict__ Y,
    const float* __restrict__ amask)
{
    __shared__ unsigned short As[128 * GLDK];
    __shared__ unsigned short Ws[128 * GLDK];

    int tid  = threadIdx.x;
    int bm   = blockIdx.y * 128, bn = blockIdx.x * 128;
    int wave = tid >> 6, lane = tid & 63;
    int l15  = lane & 15, q4 = lane >> 4;
    int wm   = (wave >> 1) * 64, wn = (wave & 1) * 64;
    int srow = tid >> 1;
    int scol = (tid & 1) * 32;
    int batch = bm >> 10;

    f32x4 acc[4][4];
    #pragma unroll
    for (int i = 0; i < 4; i++)
        #pragma unroll
        for (int j = 0; j < 4; j++) acc[i][j] = (f32x4)0.f;

    const unsigned short* ap = A + (size_t)(bm + srow) * D_MODEL + scol;
    const unsigned short* wp = W + (size_t)(bn + srow) * D_MODEL + scol;

    for (int k0 = 0; k0 < D_MODEL; k0 += 64) {
        uint4 a0 = *(const uint4*)(ap + 0),  a1 = *(const uint4*)(ap + 8);
        uint4 a2 = *(const uint4*)(ap + 16), a3 = *(const uint4*)(ap + 24);
        uint4 w0 = *(const uint4*)(wp + 0),  w1 = *(const uint4*)(wp + 8);
        uint4 w2 = *(const uint4*)(wp + 16), w3 = *(const uint4*)(wp + 24);
        ap += 64; wp += 64;
        if (amask[batch * NHEAD + (k0 >> 6)] == 0.f) {
            a0 = a1 = a2 = a3 = make_uint4(0, 0, 0, 0);
        }
        __syncthreads();
        unsigned short* as = &As[srow * GLDK + scol];
        *(uint4*)(as + 0) = a0; *(uint4*)(as + 8)  = a1;
        *(uint4*)(as + 16) = a2; *(uint4*)(as + 24) = a3;
        unsigned short* ws = &Ws[srow * GLDK + scol];
        *(uint4*)(ws + 0) = w0; *(uint4*)(ws + 8)  = w1;
        *(uint4*)(ws + 16) = w2; *(uint4*)(ws + 24) = w3;
        __syncthreads();

        #pragma unroll
        for (int kc = 0; kc < 64; kc += 32) {
            bh8 af[4], wf[4];
            #pragma unroll
            for (int i = 0; i < 4; i++)
                af[i] = *(bh8*)&As[(wm + i * 16 + l15) * GLDK + kc + q4 * 8];
            #pragma unroll
            for (int j = 0; j < 4; j++)
                wf[j] = *(bh8*)&Ws[(wn + j * 16 + l15) * GLDK + kc + q4 * 8];
            #pragma unroll
            for (int i = 0; i < 4; i++)
                #pragma unroll
                for (int j = 0; j < 4; j++)
                    acc[i][j] = __builtin_amdgcn_mfma_f32_16x16x32_bf16(af[i], wf[j], acc[i][j], 0, 0, 0);
        }
    }

    #pragma unroll
    for (int j = 0; j < 4; j++) {
        int col = bn + wn + j * 16 + l15;
        float bv = Bi[col];
        #pragma unroll
        for (int i = 0; i < 4; i++) {
            int row = bm + wm + i * 16 + q4 * 4;
            #pragma unroll
            for (int r = 0; r < 4; r++)
                Y[(size_t)(row + r) * D_MODEL + col] = acc[i][j][r] + bv;
        }
    }
}

// ---------------------------------------------------------------------------
// normqk: RMS-norm 64-elem rows (head-major fp32) and rewrite IN PLACE as
// row-interleaved bf16 hi/lo (row r bytes [r*256, r*256+256): 64 hi shorts
// then 64 lo shorts). Same split values the old attn computed on the fly.
// q (y==0) additionally gets exact top-k via ballot binary search on |x|
// bits (identical >= thresh set as reference).
// ---------------------------------------------------------------------------
__global__ void normqk(float* __restrict__ Q, float* __restrict__ Kb)
{
    int tid  = threadIdx.x;
    int wid  = tid >> 6;
    int lane = tid & 63;
    long rid = (long)blockIdx.x * 4 + wid;   // [(b*16+h)*1024 + t]
    int isK  = blockIdx.y;
    int h    = (int)((rid >> 10) & 15);

    float* p = (isK ? Kb : Q) + rid * HDIM;
    float x = p[lane];
    float ss = x * x;
    #pragma unroll
    for (int off = 32; off > 0; off >>= 1) ss += __shfl_xor(ss, off);
    float rms = sqrtf(ss * (1.0f / 64.0f));
    float xn = x / (rms + 1e-6f);

    if (!isK) {
        unsigned int ai = __float_as_uint(fabsf(xn));
        unsigned int t = 0;
        int keep = KEEPC[h];
        #pragma unroll
        for (int bit = 30; bit >= 0; --bit) {
            unsigned int cand = t | (1u << bit);
            unsigned long long b = __ballot(ai >= cand);
            if (__popcll(b) >= keep) t = cand;
        }
        if (ai < t) xn = 0.f;   // keep iff |x| >= (keep-th largest)
    }

    unsigned short hi = f2bf(xn);
    unsigned short lo = f2bf(xn - bf2f(hi));
    unsigned short* ps = (unsigned short*)p;
    ps[lane]      = hi;
    ps[64 + lane] = lo;
}

// ---------------------------------------------------------------------------
// Barrier-free MFMA flash attention. Grid (16 qt, 16 h, 4 b), 4 waves/block,
// each wave owns 16 queries (one per lane-group l15, replicated over quads).
// S^T = K·Q^T via MFMA (C-layout: col=query=l15, rows=keys in-lane) ->
// softmax needs only 2 shfls. K/Q/V fragments loaded DIRECTLY from global
// (normqk pre-split hi/lo). Only LDS: per-wave 16x72-short P^T slab.
// O^T = V^T·P^T. Zero __syncthreads.
// ---------------------------------------------------------------------------
#define PST 72

__global__ __launch_bounds__(256, 3) void attn_kernel(
    const unsigned short* __restrict__ Qsg,   // [row][128] = 64 hi | 64 lo
    const unsigned short* __restrict__ Ksg,
    const unsigned short* __restrict__ Vtg,   // [(bh)*64+d][1024] bf16
    unsigned short* __restrict__ Ctx, double* __restrict__ He)
{
    __shared__ unsigned short Ps[4][16 * PST];

    int tid = threadIdx.x;
    int qt = 15 - (int)blockIdx.x;            // heavy blocks first
    int h = blockIdx.y, b = blockIdx.z;
    int bh = b * NHEAD + h;
    size_t rbase = (size_t)bh * T_SEQ;

    int wave = tid >> 6, lane = tid & 63;
    int l15 = lane & 15, rg = lane >> 4;

    int qrow = qt * 64 + wave * 16 + l15;     // this lane's query t-index

    // hoisted Q B-fragments (hi/lo x kc) — loaded once from global
    bh8 qf[2][2];
    {
        const unsigned short* qp = Qsg + (rbase + qrow) * 128 + rg * 8;
        qf[0][0] = *(const bh8*)(qp);
        qf[0][1] = *(const bh8*)(qp + 32);
        qf[1][0] = *(const bh8*)(qp + 64);
        qf[1][1] = *(const bh8*)(qp + 96);
    }

    float m = -1e30f, l = 0.f, s2 = 0.f;
    f32x4 o[4];
    #pragma unroll
    for (int n = 0; n < 4; n++) o[n] = (f32x4)0.f;

    unsigned short* myPs = &Ps[wave][0];
    const unsigned short* vbase = Vtg + (size_t)bh * HDIM * T_SEQ;

    for (int kt = 0; kt <= qt; ++kt) {
        const unsigned short* kp = Ksg + (rbase + kt * 64) * 128;

        // ---- S^T = K · Q^T  (split-bf16, 3 passes; A=K rows, B=Q rows)
        f32x4 s[4];
        #pragma unroll
        for (int n = 0; n < 4; n++) s[n] = (f32x4)0.f;
        #pragma unroll
        for (int n = 0; n < 4; n++) {
            const unsigned short* kr = kp + (n * 16 + l15) * 128 + rg * 8;
            bh8 kh0 = *(const bh8*)(kr);
            bh8 kh1 = *(const bh8*)(kr + 32);
            bh8 kl0 = *(const bh8*)(kr + 64);
            bh8 kl1 = *(const bh8*)(kr + 96);
            s[n] = __builtin_amdgcn_mfma_f32_16x16x32_bf16(kh0, qf[0][0], s[n], 0, 0, 0);
            s[n] = __builtin_amdgcn_mfma_f32_16x16x32_bf16(kh1, qf[0][1], s[n], 0, 0, 0);
            s[n] = __builtin_amdgcn_mfma_f32_16x16x32_bf16(kh0, qf[1][0], s[n], 0, 0, 0);
            s[n] = __builtin_amdgcn_mfma_f32_16x16x32_bf16(kh1, qf[1][1], s[n], 0, 0, 0);
            s[n] = __builtin_amdgcn_mfma_f32_16x16x32_bf16(kl0, qf[0][0], s[n], 0, 0, 0);
            s[n] = __builtin_amdgcn_mfma_f32_16x16x32_bf16(kl1, qf[0][1], s[n], 0, 0, 0);
        }

        if (kt == qt) {   // causal: key (n*16+rg*4+e) > query (wave*16+l15)
            #pragma unroll
            for (int n = 0; n < 4; n++)
                #pragma unroll
                for (int e = 0; e < 4; e++)
                    if (n * 16 + rg * 4 + e > wave * 16 + l15) s[n][e] = -1e30f;
        }

        // ---- online softmax: 16 in-lane keys + 2 shfls across quads
        float mx = -1e30f;
        #pragma unroll
        for (int n = 0; n < 4; n++)
            #pragma unroll
            for (int e = 0; e < 4; e++) mx = fmaxf(mx, s[n][e]);
        mx = fmaxf(mx, __shfl_xor(mx, 16));
        mx = fmaxf(mx, __shfl_xor(mx, 32));
        float mn = fmaxf(m, mx);
        float alpha = __expf(m - mn);
        m = mn;
        float rs = 0.f, rs2 = 0.f;
        #pragma unroll
        for (int n = 0; n < 4; n++)
            #pragma unroll
            for (int e = 0; e < 4; e++) {
                float pv = __expf(s[n][e] - mn);
                s[n][e] = pv;
                rs += pv; rs2 += pv * pv;
            }
        rs  += __shfl_xor(rs, 16);  rs  += __shfl_xor(rs, 32);
        rs2 += __shfl_xor(rs2, 16); rs2 += __shfl_xor(rs2, 32);
        l  = l * alpha + rs;
        s2 = s2 * alpha * alpha + rs2;

        // ---- P^T round-trip through per-wave LDS slab (rows = queries)
        #pragma unroll
        for (int n = 0; n < 4; n++) {
            uint2 u;
            u.x = (unsigned int)f2bf(s[n][0]) | ((unsigned int)f2bf(s[n][1]) << 16);
            u.y = (unsigned int)f2bf(s[n][2]) | ((unsigned int)f2bf(s[n][3]) << 16);
            *(uint2*)&myPs[l15 * PST + n * 16 + rg * 4] = u;
        }
        bh8 pf0 = *(bh8*)&myPs[l15 * PST + rg * 8];
        bh8 pf1 = *(bh8*)&myPs[l15 * PST + 32 + rg * 8];

        // ---- O^T = V^T · P^T  (rescale first; alpha is per-lane scalar)
        #pragma unroll
        for (int n = 0; n < 4; n++) {
            o[n] *= alpha;
            const unsigned short* vr = vbase + (size_t)(n * 16 + l15) * T_SEQ + kt * 64 + rg * 8;
            bh8 v0 = *(const bh8*)(vr);
            bh8 v1 = *(const bh8*)(vr + 32);
            o[n] = __builtin_amdgcn_mfma_f32_16x16x32_bf16(v0, pf0, o[n], 0, 0, 0);
            o[n] = __builtin_amdgcn_mfma_f32_16x16x32_bf16(v1, pf1, o[n], 0, 0, 0);
        }
    }

    float linv = 1.f / l;
    float en = (rg == 0) ? s2 * linv * linv : 0.f;
    en += __shfl_xor(en, 1); en += __shfl_xor(en, 2);
    en += __shfl_xor(en, 4); en += __shfl_xor(en, 8);
    if (lane == 0) atomicAdd(&He[bh], (double)en);

    // ctx (model-major bf16): lane owns query qrow, d = n*16 + rg*4 + e
    unsigned short* cp = Ctx + ((size_t)b * T_SEQ + qrow) * D_MODEL + h * HDIM;
    #pragma unroll
    for (int n = 0; n < 4; n++) {
        uint2 u;
        u.x = (unsigned int)f2bf(o[n][0] * linv) | ((unsigned int)f2bf(o[n][1] * linv) << 16);
        u.y = (unsigned int)f2bf(o[n][2] * linv) | ((unsigned int)f2bf(o[n][3] * linv) << 16);
        *(uint2*)(cp + n * 16 + rg * 4) = u;
    }
}

// ---------------------------------------------------------------------------
// Per-batch head selection (unchanged).
// ---------------------------------------------------------------------------
__global__ void headsel(const double* __restrict__ He, float* __restrict__ Mask)
{
    int b = threadIdx.x;
    if (b >= BATCH) return;
    double e[NHEAD];
    double mx = -1e300;
    for (int h = 0; h < NHEAD; h++) {
        e[h] = He[b * NHEAD + h] / (1024.0 * 1024.0);
        mx = fmax(mx, e[h]);
    }
    double p[NHEAD], s = 0.0;
    for (int h = 0; h < NHEAD; h++) { p[h] = exp(e[h] - mx); s += p[h]; }
    double ent = 0.0;
    for (int h = 0; h < NHEAD; h++) {
        double ph = p[h] / s;
        ent -= ph * log(ph + 1e-9);
    }
    double entn = ent / log(16.0);
    entn = fmin(fmax(entn, 0.0), 1.0);
    int keep = (int)rint(2.0 + entn * 4.0);
    if (keep < 1) keep = 1;
    if (keep > NHEAD) keep = NHEAD;
    double srt[NHEAD];
    for (int h = 0; h < NHEAD; h++) srt[h] = e[h];
    for (int i = 1; i < NHEAD; i++) {
        double v = srt[i]; int j = i - 1;
        while (j >= 0 && srt[j] < v) { srt[j + 1] = srt[j]; j--; }
        srt[j + 1] = v;
    }
    double th = srt[keep - 1];
    for (int h = 0; h < NHEAD; h++)
        Mask[b * NHEAD + h] = (e[h] >= th) ? 1.0f : 0.0f;
}

// ---------------------------------------------------------------------------
extern "C" void kernel_launch(void* const* d_in, const int* in_sizes, int n_in,
                              void* d_out, int out_size, void* d_ws, size_t ws_size,
                              hipStream_t stream)
{
    (void)in_sizes; (void)n_in; (void)out_size; (void)ws_size;
    const float* x  = (const float*)d_in[0];
    const float* qw = (const float*)d_in[1];
    const float* qb = (const float*)d_in[2];
    const float* kw = (const float*)d_in[3];
    const float* kb = (const float*)d_in[4];
    const float* vw = (const float*)d_in[5];
    const float* vb = (const float*)d_in[6];
    const float* ow = (const float*)d_in[7];
    const float* ob = (const float*)d_in[8];
    float* out = (float*)d_out;

    char* base = (char*)d_ws;
    const size_t MB = (size_t)1024 * 1024;
    float*          q_hm = (float*)(base);                    // 16 MB head-major
    float*          k_hm = (float*)(base + 16 * MB);          // 16 MB head-major
    unsigned short* vt   = (unsigned short*)(base + 32 * MB); // 8 MB V^T bf16
    unsigned short* ctxb = (unsigned short*)(base + 40 * MB); // 8 MB bf16
    unsigned short* kwh  = (unsigned short*)(base + 48 * MB); // 2 MB
    unsigned short* kwl  = (unsigned short*)(base + 50 * MB);
    unsigned short* vwb  = (unsigned short*)(base + 52 * MB);
    unsigned short* owb  = (unsigned short*)(base + 54 * MB);
    double*         he   = (double*)(base + 56 * MB);
    float*          mask = (float*)(base + 56 * MB + 512);
    signed char*    dig  = (signed char*)(base + 32 * MB);    // 16 MB (overlaid)
    signed char*    sg   = (signed char*)(base + 57 * MB);    // 1 MB

    hipMemsetAsync(he, 0, 64 * sizeof(double), stream);

    cast_weights<<<1536, 256, 0, stream>>>(kw, kwh, kwl, vw, vwb, ow, owb);
    prep_q<<<2560, 256, 0, stream>>>(x, dig, qw, sg);
    // q projection: exact int8-digit MFMA (consumes dig before vt overlay)
    gemm_q_i8<<<dim3(16, 64), 256, 0, stream>>>(dig, sg, qb, q_hm);
    // k projection: split-bf16 MFMA, fp32 head-major out
    gemm_xsplit<<<dim3(8, 32), 256, 0, stream>>>(x, kwh, kwl, kb, k_hm, nullptr, 1);
    // v projection: bf16 MFMA, V^T bf16 out
    gemm_xsplit<<<dim3(8, 32), 256, 0, stream>>>(x, vwb, nullptr, vb, nullptr, vt, 0);
    // norm + top-k, rewrite q/k in place as interleaved bf16 hi/lo splits
    normqk<<<dim3(16384, 2), 256, 0, stream>>>(q_hm, k_hm);
    attn_kernel<<<dim3(16, 16, 4), 256, 0, stream>>>(
        (const unsigned short*)q_hm, (const unsigned short*)k_hm, vt, ctxb, he);
    headsel<<<1, 64, 0, stream>>>(he, mask);
    gemm_obf<<<dim3(8, 32), 256, 0, stream>>>(ctxb, owb, ob, out, mask);
}

// Round 7
// 394.586 us; speedup vs baseline: 1.2874x; 1.2874x over previous
//
#include <hip/hip_runtime.h>
#include <math.h>

#define D_MODEL 1024
#define T_SEQ   1024
#define BATCH   4
#define NHEAD   16
#define HDIM    64

// keep counts: trunc(linspace(0.35,0.15,16)*64), min 1
__constant__ int KEEPC[16] = {22,21,20,19,18,18,17,16,15,14,13,13,12,11,10,9};

typedef short bh8  __attribute__((ext_vector_type(8)));
typedef float f32x4 __attribute__((ext_vector_type(4)));
typedef int   i32x4 __attribute__((ext_vector_type(4)));

__device__ __forceinline__ unsigned short f2bf(float f) {
    unsigned int u = __float_as_uint(f);
    return (unsigned short)((u + 0x7FFFu + ((u >> 16) & 1u)) >> 16);
}
__device__ __forceinline__ float bf2f(unsigned short h) {
    return __uint_as_float(((unsigned int)h) << 16);
}

// ---------------------------------------------------------------------------
// Cast weights once: kw -> (hi,lo) bf16 split; vw, ow -> single bf16.
// ---------------------------------------------------------------------------
__global__ void cast_weights(const float* __restrict__ kw,
                             unsigned short* __restrict__ kwh,
                             unsigned short* __restrict__ kwl,
                             const float* __restrict__ vw,
                             unsigned short* __restrict__ vwb,
                             const float* __restrict__ ow,
                             unsigned short* __restrict__ owb)
{
    const int NS = (D_MODEL * D_MODEL) / 8;
    int i = blockIdx.x * 256 + threadIdx.x;
    const float* src; unsigned short* dh; unsigned short* dl = nullptr;
    long off;
    if (i < NS)           { src = kw; dh = kwh; dl = kwl; off = i; }
    else if (i < 2 * NS)  { src = vw; dh = vwb; off = i - NS; }
    else if (i < 3 * NS)  { src = ow; dh = owb; off = i - 2 * NS; }
    else return;
    long e = off * 8;
    alignas(16) float fl[8];
    *(float4*)&fl[0] = *(const float4*)(src + e);
    *(float4*)&fl[4] = *(const float4*)(src + e + 4);
    uint4 hp, lp;
    unsigned int* hpw = (unsigned int*)&hp;
    unsigned int* lpw = (unsigned int*)&lp;
    #pragma unroll
    for (int c = 0; c < 4; c++) {
        unsigned short h0 = f2bf(fl[2 * c]), h1 = f2bf(fl[2 * c + 1]);
        hpw[c] = (unsigned int)h0 | ((unsigned int)h1 << 16);
        if (dl) {
            unsigned short l0 = f2bf(fl[2 * c] - bf2f(h0));
            unsigned short l1 = f2bf(fl[2 * c + 1] - bf2f(h1));
            lpw[c] = (unsigned int)l0 | ((unsigned int)l1 << 16);
        }
    }
    *(uint4*)(dh + e) = hp;
    if (dl) *(uint4*)(dl + e) = lp;
}

// ---------------------------------------------------------------------------
// prep_q: x -> 4 signed base-256 digit planes of n = rint(x * 2^23)
// (exact), and qw -> sign int8.
// ---------------------------------------------------------------------------
__global__ void prep_q(const float* __restrict__ x, signed char* __restrict__ dig,
                       const float* __restrict__ qw, signed char* __restrict__ sg)
{
    const int NX = (BATCH * T_SEQ * D_MODEL) / 8;   // 524288
    const int NW = (D_MODEL * D_MODEL) / 8;         // 131072
    const long PL = (long)BATCH * T_SEQ * D_MODEL;  // plane stride 4194304
    int i = blockIdx.x * 256 + threadIdx.x;
    if (i < NX) {
        long e = (long)i * 8;
        alignas(16) float f[8];
        *(float4*)&f[0] = *(const float4*)(x + e);
        *(float4*)&f[4] = *(const float4*)(x + e + 4);
        signed char d[4][8];
        #pragma unroll
        for (int c = 0; c < 8; c++) {
            int n = (int)rintf(f[c] * 8388608.0f);
            int d0 = (signed char)(n & 0xff); n = (n - d0) >> 8;
            int d1 = (signed char)(n & 0xff); n = (n - d1) >> 8;
            int d2 = (signed char)(n & 0xff); n = (n - d2) >> 8;
            d[0][c] = (signed char)d0; d[1][c] = (signed char)d1;
            d[2][c] = (signed char)d2; d[3][c] = (signed char)n;
        }
        #pragma unroll
        for (int p = 0; p < 4; p++)
            *(uint2*)(dig + p * PL + e) = *(uint2*)&d[p][0];
    } else if (i < NX + NW) {
        long e = (long)(i - NX) * 8;
        alignas(16) float f[8];
        *(float4*)&f[0] = *(const float4*)(qw + e);
        *(float4*)&f[4] = *(const float4*)(qw + e + 4);
        signed char s[8];
        #pragma unroll
        for (int c = 0; c < 8; c++)
            s[c] = (signed char)((f[c] > 0.f) - (f[c] < 0.f));
        *(uint2*)(sg + e) = *(uint2*)&s[0];
    }
}

// ---------------------------------------------------------------------------
// Q projection via EXACT int8 MFMA: q = 2^-23 * sum_p 256^p (Dp @ S^T) + b.
// Output fp32 HEAD-MAJOR: [(b*16+h)*1024 + t][d].
// ---------------------------------------------------------------------------
#define QST 80

__global__ __launch_bounds__(256, 2) void gemm_q_i8(
    const signed char* __restrict__ dig, const signed char* __restrict__ sg,
    const float* __restrict__ Bi, float* __restrict__ Y)
{
    __shared__ signed char Ad[4][64 * QST];
    __shared__ signed char Bs[64 * QST];

    const long PL = (long)BATCH * T_SEQ * D_MODEL;
    int tid  = threadIdx.x;
    int bm   = blockIdx.y * 64, bn = blockIdx.x * 64;
    int wave = tid >> 6, lane = tid & 63;
    int l15  = lane & 15, rg = lane >> 4;
    int wm   = (wave >> 1) * 32, wn = (wave & 1) * 32;
    int srow = tid >> 2;
    int skof = (tid & 3) * 16;

    i32x4 acc[4][2][2];
    #pragma unroll
    for (int p = 0; p < 4; p++)
        #pragma unroll
        for (int i = 0; i < 2; i++)
            #pragma unroll
            for (int j = 0; j < 2; j++) acc[p][i][j] = (i32x4)0;

    const signed char* ap = dig + (size_t)(bm + srow) * D_MODEL + skof;
    const signed char* bp = sg + (size_t)(bn + srow) * D_MODEL + skof;

    for (int k0 = 0; k0 < D_MODEL; k0 += 64) {
        uint4 av[4], bv;
        #pragma unroll
        for (int p = 0; p < 4; p++) av[p] = *(const uint4*)(ap + p * PL);
        bv = *(const uint4*)(bp);
        ap += 64; bp += 64;

        __syncthreads();
        #pragma unroll
        for (int p = 0; p < 4; p++)
            *(uint4*)&Ad[p][srow * QST + skof] = av[p];
        *(uint4*)&Bs[srow * QST + skof] = bv;
        __syncthreads();

        i32x4 bf[2];
        #pragma unroll
        for (int j = 0; j < 2; j++)
            bf[j] = *(i32x4*)&Bs[(wn + j * 16 + l15) * QST + rg * 16];
        #pragma unroll
        for (int p = 0; p < 4; p++) {
            i32x4 af[2];
            #pragma unroll
            for (int i = 0; i < 2; i++)
                af[i] = *(i32x4*)&Ad[p][(wm + i * 16 + l15) * QST + rg * 16];
            #pragma unroll
            for (int i = 0; i < 2; i++)
                #pragma unroll
                for (int j = 0; j < 2; j++)
                    acc[p][i][j] = __builtin_amdgcn_mfma_i32_16x16x64_i8(
                        af[i], bf[j], acc[p][i][j], 0, 0, 0);
        }
    }

    int hh = bn >> 6;
    #pragma unroll
    for (int j = 0; j < 2; j++) {
        int col = bn + wn + j * 16 + l15;
        int dd = col & 63;
        float bvv = Bi[col];
        #pragma unroll
        for (int i = 0; i < 2; i++) {
            #pragma unroll
            for (int r = 0; r < 4; r++) {
                int row = bm + wm + i * 16 + rg * 4 + r;
                int bb = row >> 10, tt = row & 1023;
                long t = (long)acc[0][i][j][r]
                       + ((long)acc[1][i][j][r] << 8)
                       + ((long)acc[2][i][j][r] << 16)
                       + ((long)acc[3][i][j][r] << 24);
                float o = (float)((double)t * (1.0 / 8388608.0)) + bvv;
                Y[(((size_t)(bb * NHEAD + hh)) * T_SEQ + tt) * HDIM + dd] = o;
            }
        }
    }
}

// ---------------------------------------------------------------------------
// MFMA GEMM, bf16 split of fp32 A on the fly.
// split=1 (k-proj): 3-pass hi/lo product, fp32 out HEAD-MAJOR into Yf.
// split=0 (v-proj): single bf16 pass, bf16 out TRANSPOSED head-major Yv.
// ---------------------------------------------------------------------------
#define GLDK 72

__global__ __launch_bounds__(256, 2) void gemm_xsplit(
    const float* __restrict__ A, const unsigned short* __restrict__ Wh,
    const unsigned short* __restrict__ Wl, const float* __restrict__ Bi,
    float* __restrict__ Yf, unsigned short* __restrict__ Yv, int split)
{
    __shared__ unsigned short Ah[128 * GLDK];
    __shared__ unsigned short Al[128 * GLDK];
    __shared__ unsigned short Whs[128 * GLDK];
    __shared__ unsigned short Wls[128 * GLDK];

    int tid  = threadIdx.x;
    int bm   = blockIdx.y * 128, bn = blockIdx.x * 128;
    int wave = tid >> 6, lane = tid & 63;
    int l15  = lane & 15, q4 = lane >> 4;
    int wm   = (wave >> 1) * 64, wn = (wave & 1) * 64;
    int srow = tid >> 1;
    int scol = (tid & 1) * 32;

    f32x4 acc[4][4];
    #pragma unroll
    for (int i = 0; i < 4; i++)
        #pragma unroll
        for (int j = 0; j < 4; j++) acc[i][j] = (f32x4)0.f;

    const float* ap = A + (size_t)(bm + srow) * D_MODEL + scol;
    const unsigned short* whp = Wh + (size_t)(bn + srow) * D_MODEL + scol;
    const unsigned short* wlp = (split ? Wl : Wh) + (size_t)(bn + srow) * D_MODEL + scol;

    for (int k0 = 0; k0 < D_MODEL; k0 += 64) {
        alignas(16) float fl[32];
        #pragma unroll
        for (int c = 0; c < 8; c++) *(float4*)&fl[4 * c] = *(const float4*)(ap + 4 * c);
        uint4 w0 = *(const uint4*)(whp + 0),  w1 = *(const uint4*)(whp + 8);
        uint4 w2 = *(const uint4*)(whp + 16), w3 = *(const uint4*)(whp + 24);
        uint4 x0, x1, x2, x3;
        if (split) {
            x0 = *(const uint4*)(wlp + 0);  x1 = *(const uint4*)(wlp + 8);
            x2 = *(const uint4*)(wlp + 16); x3 = *(const uint4*)(wlp + 24);
        }
        ap += 64; whp += 64; wlp += 64;

        unsigned int hw[16], lw[16];
        #pragma unroll
        for (int c = 0; c < 16; c++) {
            unsigned short h0 = f2bf(fl[2 * c]), h1 = f2bf(fl[2 * c + 1]);
            hw[c] = (unsigned int)h0 | ((unsigned int)h1 << 16);
            if (split) {
                unsigned short l0 = f2bf(fl[2 * c] - bf2f(h0));
                unsigned short l1 = f2bf(fl[2 * c + 1] - bf2f(h1));
                lw[c] = (unsigned int)l0 | ((unsigned int)l1 << 16);
            }
        }

        __syncthreads();
        unsigned int* ah = (unsigned int*)&Ah[srow * GLDK + scol];
        #pragma unroll
        for (int g = 0; g < 4; g++)
            *(uint4*)(ah + 4 * g) = make_uint4(hw[4 * g], hw[4 * g + 1], hw[4 * g + 2], hw[4 * g + 3]);
        if (split) {
            unsigned int* al = (unsigned int*)&Al[srow * GLDK + scol];
            #pragma unroll
            for (int g = 0; g < 4; g++)
                *(uint4*)(al + 4 * g) = make_uint4(lw[4 * g], lw[4 * g + 1], lw[4 * g + 2], lw[4 * g + 3]);
        }
        unsigned short* ws = &Whs[srow * GLDK + scol];
        *(uint4*)(ws + 0) = w0; *(uint4*)(ws + 8)  = w1;
        *(uint4*)(ws + 16) = w2; *(uint4*)(ws + 24) = w3;
        if (split) {
            unsigned short* wl2 = &Wls[srow * GLDK + scol];
            *(uint4*)(wl2 + 0) = x0; *(uint4*)(wl2 + 8)  = x1;
            *(uint4*)(wl2 + 16) = x2; *(uint4*)(wl2 + 24) = x3;
        }
        __syncthreads();

        #pragma unroll
        for (int kc = 0; kc < 64; kc += 32) {
            bh8 ahf[4], whf[4];
            #pragma unroll
            for (int i = 0; i < 4; i++)
                ahf[i] = *(bh8*)&Ah[(wm + i * 16 + l15) * GLDK + kc + q4 * 8];
            #pragma unroll
            for (int j = 0; j < 4; j++)
                whf[j] = *(bh8*)&Whs[(wn + j * 16 + l15) * GLDK + kc + q4 * 8];
            #pragma unroll
            for (int i = 0; i < 4; i++)
                #pragma unroll
                for (int j = 0; j < 4; j++)
                    acc[i][j] = __builtin_amdgcn_mfma_f32_16x16x32_bf16(ahf[i], whf[j], acc[i][j], 0, 0, 0);
            if (split) {
                bh8 alf[4], wlf[4];
                #pragma unroll
                for (int i = 0; i < 4; i++)
                    alf[i] = *(bh8*)&Al[(wm + i * 16 + l15) * GLDK + kc + q4 * 8];
                #pragma unroll
                for (int j = 0; j < 4; j++)
                    wlf[j] = *(bh8*)&Wls[(wn + j * 16 + l15) * GLDK + kc + q4 * 8];
                #pragma unroll
                for (int i = 0; i < 4; i++)
                    #pragma unroll
                    for (int j = 0; j < 4; j++) {
                        acc[i][j] = __builtin_amdgcn_mfma_f32_16x16x32_bf16(ahf[i], wlf[j], acc[i][j], 0, 0, 0);
                        acc[i][j] = __builtin_amdgcn_mfma_f32_16x16x32_bf16(alf[i], whf[j], acc[i][j], 0, 0, 0);
                    }
            }
        }
    }

    #pragma unroll
    for (int j = 0; j < 4; j++) {
        int col = bn + wn + j * 16 + l15;
        int hh = col >> 6, dd = col & 63;
        float bv = Bi[col];
        #pragma unroll
        for (int i = 0; i < 4; i++) {
            int row0 = bm + wm + i * 16 + q4 * 4;
            int bb = row0 >> 10, tt = row0 & 1023;
            if (split) {
                float* yp = Yf + (((size_t)(bb * NHEAD + hh)) * T_SEQ + tt) * HDIM + dd;
                #pragma unroll
                for (int r = 0; r < 4; r++)
                    yp[(size_t)r * HDIM] = acc[i][j][r] + bv;
            } else {
                uint2 u;
                u.x = (unsigned int)f2bf(acc[i][j][0] + bv) | ((unsigned int)f2bf(acc[i][j][1] + bv) << 16);
                u.y = (unsigned int)f2bf(acc[i][j][2] + bv) | ((unsigned int)f2bf(acc[i][j][3] + bv) << 16);
                *(uint2*)(Yv + ((size_t)(bb * NHEAD + hh) * HDIM + dd) * T_SEQ + tt) = u;
            }
        }
    }
}

// ---------------------------------------------------------------------------
// Out-projection: bf16 ctx (model-major) @ bf16 W^T + bias, head mask on A.
// ---------------------------------------------------------------------------
__global__ __launch_bounds__(256, 2) void gemm_obf(
    const unsigned short* __restrict__ A, const unsigned short* __restrict__ W,
    const float* __restrict__ Bi, float* __restrict__ Y,
    const float* __restrict__ amask)
{
    __shared__ unsigned short As[128 * GLDK];
    __shared__ unsigned short Ws[128 * GLDK];

    int tid  = threadIdx.x;
    int bm   = blockIdx.y * 128, bn = blockIdx.x * 128;
    int wave = tid >> 6, lane = tid & 63;
    int l15  = lane & 15, q4 = lane >> 4;
    int wm   = (wave >> 1) * 64, wn = (wave & 1) * 64;
    int srow = tid >> 1;
    int scol = (tid & 1) * 32;
    int batch = bm >> 10;

    f32x4 acc[4][4];
    #pragma unroll
    for (int i = 0; i < 4; i++)
        #pragma unroll
        for (int j = 0; j < 4; j++) acc[i][j] = (f32x4)0.f;

    const unsigned short* ap = A + (size_t)(bm + srow) * D_MODEL + scol;
    const unsigned short* wp = W + (size_t)(bn + srow) * D_MODEL + scol;

    for (int k0 = 0; k0 < D_MODEL; k0 += 64) {
        uint4 a0 = *(const uint4*)(ap + 0),  a1 = *(const uint4*)(ap + 8);
        uint4 a2 = *(const uint4*)(ap + 16), a3 = *(const uint4*)(ap + 24);
        uint4 w0 = *(const uint4*)(wp + 0),  w1 = *(const uint4*)(wp + 8);
        uint4 w2 = *(const uint4*)(wp + 16), w3 = *(const uint4*)(wp + 24);
        ap += 64; wp += 64;
        if (amask[batch * NHEAD + (k0 >> 6)] == 0.f) {
            a0 = a1 = a2 = a3 = make_uint4(0, 0, 0, 0);
        }
        __syncthreads();
        unsigned short* as = &As[srow * GLDK + scol];
        *(uint4*)(as + 0) = a0; *(uint4*)(as + 8)  = a1;
        *(uint4*)(as + 16) = a2; *(uint4*)(as + 24) = a3;
        unsigned short* ws = &Ws[srow * GLDK + scol];
        *(uint4*)(ws + 0) = w0; *(uint4*)(ws + 8)  = w1;
        *(uint4*)(ws + 16) = w2; *(uint4*)(ws + 24) = w3;
        __syncthreads();

        #pragma unroll
        for (int kc = 0; kc < 64; kc += 32) {
            bh8 af[4], wf[4];
            #pragma unroll
            for (int i = 0; i < 4; i++)
                af[i] = *(bh8*)&As[(wm + i * 16 + l15) * GLDK + kc + q4 * 8];
            #pragma unroll
            for (int j = 0; j < 4; j++)
                wf[j] = *(bh8*)&Ws[(wn + j * 16 + l15) * GLDK + kc + q4 * 8];
            #pragma unroll
            for (int i = 0; i < 4; i++)
                #pragma unroll
                for (int j = 0; j < 4; j++)
                    acc[i][j] = __builtin_amdgcn_mfma_f32_16x16x32_bf16(af[i], wf[j], acc[i][j], 0, 0, 0);
        }
    }

    #pragma unroll
    for (int j = 0; j < 4; j++) {
        int col = bn + wn + j * 16 + l15;
        float bv = Bi[col];
        #pragma unroll
        for (int i = 0; i < 4; i++) {
            int row = bm + wm + i * 16 + q4 * 4;
            #pragma unroll
            for (int r = 0; r < 4; r++)
                Y[(size_t)(row + r) * D_MODEL + col] = acc[i][j][r] + bv;
        }
    }
}

// ---------------------------------------------------------------------------
// normqk: RMS-norm 64-elem rows (head-major fp32) and rewrite IN PLACE as
// row-interleaved bf16 hi/lo (row r: 64 hi shorts then 64 lo shorts).
// q (y==0) additionally gets exact top-k via ballot binary search.
// ---------------------------------------------------------------------------
__global__ void normqk(float* __restrict__ Q, float* __restrict__ Kb)
{
    int tid  = threadIdx.x;
    int wid  = tid >> 6;
    int lane = tid & 63;
    long rid = (long)blockIdx.x * 4 + wid;   // [(b*16+h)*1024 + t]
    int isK  = blockIdx.y;
    int h    = (int)((rid >> 10) & 15);

    float* p = (isK ? Kb : Q) + rid * HDIM;
    float x = p[lane];
    float ss = x * x;
    #pragma unroll
    for (int off = 32; off > 0; off >>= 1) ss += __shfl_xor(ss, off);
    float rms = sqrtf(ss * (1.0f / 64.0f));
    float xn = x / (rms + 1e-6f);

    if (!isK) {
        unsigned int ai = __float_as_uint(fabsf(xn));
        unsigned int t = 0;
        int keep = KEEPC[h];
        #pragma unroll
        for (int bit = 30; bit >= 0; --bit) {
            unsigned int cand = t | (1u << bit);
            unsigned long long b = __ballot(ai >= cand);
            if (__popcll(b) >= keep) t = cand;
        }
        if (ai < t) xn = 0.f;   // keep iff |x| >= (keep-th largest)
    }

    unsigned short hi = f2bf(xn);
    unsigned short lo = f2bf(xn - bf2f(hi));
    unsigned short* ps = (unsigned short*)p;
    ps[lane]      = hi;
    ps[64 + lane] = lo;
}

// ---------------------------------------------------------------------------
// MFMA flash attention, transposed S + cooperative LDS staging.
// Grid (16 qt, 16 h, 4 b), 4 waves/block, each wave owns 16 queries.
// S^T = K·Q^T (A=K rows from LDS, B=Q rows hoisted from global): C-layout
// puts one query per lane (col=l15) -> online softmax is per-lane scalar
// with only 2 shfls. K-hi/lo and V^T staged cooperatively (coalesced 16B),
// 2 barriers/iter. P round-trip via per-wave LDS slab (no barrier).
// O^T = V^T·P^T. Emits ctx bf16 and sum(attn^2) per head (f64 atomics).
// ---------------------------------------------------------------------------
#define KST 72   // LDS row stride in shorts (144 B; 2-way bank alias = free)

__global__ __launch_bounds__(256, 4) void attn_kernel(
    const unsigned short* __restrict__ Qsg,   // [row][128] = 64 hi | 64 lo
    const unsigned short* __restrict__ Ksg,
    const unsigned short* __restrict__ Vtg,   // [(bh)*64+d][1024] bf16
    unsigned short* __restrict__ Ctx, double* __restrict__ He)
{
    __shared__ unsigned short Kh[64 * KST];
    __shared__ unsigned short Kl[64 * KST];
    __shared__ unsigned short Vt[64 * KST];
    __shared__ unsigned short Ps[4][16 * KST];

    int tid = threadIdx.x;
    int qt = 15 - (int)blockIdx.x;            // heavy blocks first
    int h = blockIdx.y, b = blockIdx.z;
    int bh = b * NHEAD + h;
    size_t rbase = (size_t)bh * T_SEQ;

    int wave = tid >> 6, lane = tid & 63;
    int l15 = lane & 15, rg = lane >> 4;
    int srow = tid >> 2;                      // staging row 0..63
    int scol = (tid & 3) * 16;                // staging col offset (shorts)

    int qrow = qt * 64 + wave * 16 + l15;     // this lane's query t-index

    // hoisted Q B-fragments (hi/lo x kc) — loaded once from global
    bh8 qf[2][2];
    {
        const unsigned short* qp = Qsg + (rbase + qrow) * 128 + rg * 8;
        qf[0][0] = *(const bh8*)(qp);
        qf[0][1] = *(const bh8*)(qp + 32);
        qf[1][0] = *(const bh8*)(qp + 64);
        qf[1][1] = *(const bh8*)(qp + 96);
    }

    float m = -1e30f, l = 0.f, s2 = 0.f;
    f32x4 o[4];
    #pragma unroll
    for (int n = 0; n < 4; n++) o[n] = (f32x4)0.f;

    unsigned short* myPs = &Ps[wave][0];
    const unsigned short* vbase = Vtg + (size_t)bh * HDIM * T_SEQ;

    for (int kt = 0; kt <= qt; ++kt) {
        // ---- cooperative staging (coalesced 16B loads)
        const unsigned short* krow = Ksg + (rbase + kt * 64 + srow) * 128;
        uint4 kh0 = *(const uint4*)(krow + scol);
        uint4 kh1 = *(const uint4*)(krow + scol + 8);
        uint4 kl0 = *(const uint4*)(krow + 64 + scol);
        uint4 kl1 = *(const uint4*)(krow + 64 + scol + 8);
        const unsigned short* vrow = vbase + (size_t)srow * T_SEQ + kt * 64 + scol;
        uint4 vv0 = *(const uint4*)(vrow);
        uint4 vv1 = *(const uint4*)(vrow + 8);

        __syncthreads();   // prior iteration's LDS reads done
        *(uint4*)&Kh[srow * KST + scol]     = kh0;
        *(uint4*)&Kh[srow * KST + scol + 8] = kh1;
        *(uint4*)&Kl[srow * KST + scol]     = kl0;
        *(uint4*)&Kl[srow * KST + scol + 8] = kl1;
        *(uint4*)&Vt[srow * KST + scol]     = vv0;
        *(uint4*)&Vt[srow * KST + scol + 8] = vv1;
        __syncthreads();

        // ---- S^T = K · Q^T  (split-bf16, 3 passes; A=K rows, B=Q rows)
        f32x4 s[4];
        #pragma unroll
        for (int n = 0; n < 4; n++) s[n] = (f32x4)0.f;
        #pragma unroll
        for (int n = 0; n < 4; n++) {
            const unsigned short* kr = &Kh[(n * 16 + l15) * KST + rg * 8];
            const unsigned short* lr = &Kl[(n * 16 + l15) * KST + rg * 8];
            bh8 ah0 = *(const bh8*)(kr);
            bh8 ah1 = *(const bh8*)(kr + 32);
            bh8 al0 = *(const bh8*)(lr);
            bh8 al1 = *(const bh8*)(lr + 32);
            s[n] = __builtin_amdgcn_mfma_f32_16x16x32_bf16(ah0, qf[0][0], s[n], 0, 0, 0);
            s[n] = __builtin_amdgcn_mfma_f32_16x16x32_bf16(ah1, qf[0][1], s[n], 0, 0, 0);
            s[n] = __builtin_amdgcn_mfma_f32_16x16x32_bf16(ah0, qf[1][0], s[n], 0, 0, 0);
            s[n] = __builtin_amdgcn_mfma_f32_16x16x32_bf16(ah1, qf[1][1], s[n], 0, 0, 0);
            s[n] = __builtin_amdgcn_mfma_f32_16x16x32_bf16(al0, qf[0][0], s[n], 0, 0, 0);
            s[n] = __builtin_amdgcn_mfma_f32_16x16x32_bf16(al1, qf[0][1], s[n], 0, 0, 0);
        }

        if (kt == qt) {   // causal: key (n*16+rg*4+e) > query (wave*16+l15)
            #pragma unroll
            for (int n = 0; n < 4; n++)
                #pragma unroll
                for (int e = 0; e < 4; e++)
                    if (n * 16 + rg * 4 + e > wave * 16 + l15) s[n][e] = -1e30f;
        }

        // ---- online softmax: 16 in-lane keys + 2 shfls across quads
        float mx = -1e30f;
        #pragma unroll
        for (int n = 0; n < 4; n++)
            #pragma unroll
            for (int e = 0; e < 4; e++) mx = fmaxf(mx, s[n][e]);
        mx = fmaxf(mx, __shfl_xor(mx, 16));
        mx = fmaxf(mx, __shfl_xor(mx, 32));
        float mn = fmaxf(m, mx);
        float alpha = __expf(m - mn);
        m = mn;
        float rs = 0.f, rs2 = 0.f;
        #pragma unroll
        for (int n = 0; n < 4; n++)
            #pragma unroll
            for (int e = 0; e < 4; e++) {
                float pv = __expf(s[n][e] - mn);
                s[n][e] = pv;
                rs += pv; rs2 += pv * pv;
            }
        rs  += __shfl_xor(rs, 16);  rs  += __shfl_xor(rs, 32);
        rs2 += __shfl_xor(rs2, 16); rs2 += __shfl_xor(rs2, 32);
        l  = l * alpha + rs;
        s2 = s2 * alpha * alpha + rs2;

        // ---- P^T round-trip through per-wave LDS slab (rows = queries)
        #pragma unroll
        for (int n = 0; n < 4; n++) {
            uint2 u;
            u.x = (unsigned int)f2bf(s[n][0]) | ((unsigned int)f2bf(s[n][1]) << 16);
            u.y = (unsigned int)f2bf(s[n][2]) | ((unsigned int)f2bf(s[n][3]) << 16);
            *(uint2*)&myPs[l15 * KST + n * 16 + rg * 4] = u;
        }
        bh8 pf0 = *(bh8*)&myPs[l15 * KST + rg * 8];
        bh8 pf1 = *(bh8*)&myPs[l15 * KST + 32 + rg * 8];

        // ---- O^T = V^T · P^T  (rescale first; alpha is per-lane scalar)
        #pragma unroll
        for (int n = 0; n < 4; n++) {
            o[n] *= alpha;
            const unsigned short* vr = &Vt[(n * 16 + l15) * KST + rg * 8];
            bh8 v0 = *(const bh8*)(vr);
            bh8 v1 = *(const bh8*)(vr + 32);
            o[n] = __builtin_amdgcn_mfma_f32_16x16x32_bf16(v0, pf0, o[n], 0, 0, 0);
            o[n] = __builtin_amdgcn_mfma_f32_16x16x32_bf16(v1, pf1, o[n], 0, 0, 0);
        }
    }

    float linv = 1.f / l;
    float en = (rg == 0) ? s2 * linv * linv : 0.f;
    en += __shfl_xor(en, 1); en += __shfl_xor(en, 2);
    en += __shfl_xor(en, 4); en += __shfl_xor(en, 8);
    if (lane == 0) atomicAdd(&He[bh], (double)en);

    // ctx (model-major bf16): lane owns query qrow, d = n*16 + rg*4 + e
    unsigned short* cp = Ctx + ((size_t)b * T_SEQ + qrow) * D_MODEL + h * HDIM;
    #pragma unroll
    for (int n = 0; n < 4; n++) {
        uint2 u;
        u.x = (unsigned int)f2bf(o[n][0] * linv) | ((unsigned int)f2bf(o[n][1] * linv) << 16);
        u.y = (unsigned int)f2bf(o[n][2] * linv) | ((unsigned int)f2bf(o[n][3] * linv) << 16);
        *(uint2*)(cp + n * 16 + rg * 4) = u;
    }
}

// ---------------------------------------------------------------------------
// Per-batch head selection (unchanged).
// ---------------------------------------------------------------------------
__global__ void headsel(const double* __restrict__ He, float* __restrict__ Mask)
{
    int b = threadIdx.x;
    if (b >= BATCH) return;
    double e[NHEAD];
    double mx = -1e300;
    for (int h = 0; h < NHEAD; h++) {
        e[h] = He[b * NHEAD + h] / (1024.0 * 1024.0);
        mx = fmax(mx, e[h]);
    }
    double p[NHEAD], s = 0.0;
    for (int h = 0; h < NHEAD; h++) { p[h] = exp(e[h] - mx); s += p[h]; }
    double ent = 0.0;
    for (int h = 0; h < NHEAD; h++) {
        double ph = p[h] / s;
        ent -= ph * log(ph + 1e-9);
    }
    double entn = ent / log(16.0);
    entn = fmin(fmax(entn, 0.0), 1.0);
    int keep = (int)rint(2.0 + entn * 4.0);
    if (keep < 1) keep = 1;
    if (keep > NHEAD) keep = NHEAD;
    double srt[NHEAD];
    for (int h = 0; h < NHEAD; h++) srt[h] = e[h];
    for (int i = 1; i < NHEAD; i++) {
        double v = srt[i]; int j = i - 1;
        while (j >= 0 && srt[j] < v) { srt[j + 1] = srt[j]; j--; }
        srt[j + 1] = v;
    }
    double th = srt[keep - 1];
    for (int h = 0; h < NHEAD; h++)
        Mask[b * NHEAD + h] = (e[h] >= th) ? 1.0f : 0.0f;
}

// ---------------------------------------------------------------------------
extern "C" void kernel_launch(void* const* d_in, const int* in_sizes, int n_in,
                              void* d_out, int out_size, void* d_ws, size_t ws_size,
                              hipStream_t stream)
{
    (void)in_sizes; (void)n_in; (void)out_size; (void)ws_size;
    const float* x  = (const float*)d_in[0];
    const float* qw = (const float*)d_in[1];
    const float* qb = (const float*)d_in[2];
    const float* kw = (const float*)d_in[3];
    const float* kb = (const float*)d_in[4];
    const float* vw = (const float*)d_in[5];
    const float* vb = (const float*)d_in[6];
    const float* ow = (const float*)d_in[7];
    const float* ob = (const float*)d_in[8];
    float* out = (float*)d_out;

    char* base = (char*)d_ws;
    const size_t MB = (size_t)1024 * 1024;
    float*          q_hm = (float*)(base);                    // 16 MB head-major
    float*          k_hm = (float*)(base + 16 * MB);          // 16 MB head-major
    unsigned short* vt   = (unsigned short*)(base + 32 * MB); // 8 MB V^T bf16
    unsigned short* ctxb = (unsigned short*)(base + 40 * MB); // 8 MB bf16
    unsigned short* kwh  = (unsigned short*)(base + 48 * MB); // 2 MB
    unsigned short* kwl  = (unsigned short*)(base + 50 * MB);
    unsigned short* vwb  = (unsigned short*)(base + 52 * MB);
    unsigned short* owb  = (unsigned short*)(base + 54 * MB);
    double*         he   = (double*)(base + 56 * MB);
    float*          mask = (float*)(base + 56 * MB + 512);
    signed char*    dig  = (signed char*)(base + 32 * MB);    // 16 MB (overlaid)
    signed char*    sg   = (signed char*)(base + 57 * MB);    // 1 MB

    hipMemsetAsync(he, 0, 64 * sizeof(double), stream);

    cast_weights<<<1536, 256, 0, stream>>>(kw, kwh, kwl, vw, vwb, ow, owb);
    prep_q<<<2560, 256, 0, stream>>>(x, dig, qw, sg);
    // q projection: exact int8-digit MFMA (consumes dig before vt overlay)
    gemm_q_i8<<<dim3(16, 64), 256, 0, stream>>>(dig, sg, qb, q_hm);
    // k projection: split-bf16 MFMA, fp32 head-major out
    gemm_xsplit<<<dim3(8, 32), 256, 0, stream>>>(x, kwh, kwl, kb, k_hm, nullptr, 1);
    // v projection: bf16 MFMA, V^T bf16 out
    gemm_xsplit<<<dim3(8, 32), 256, 0, stream>>>(x, vwb, nullptr, vb, nullptr, vt, 0);
    // norm + top-k, rewrite q/k in place as interleaved bf16 hi/lo splits
    normqk<<<dim3(16384, 2), 256, 0, stream>>>(q_hm, k_hm);
    attn_kernel<<<dim3(16, 16, 4), 256, 0, stream>>>(
        (const unsigned short*)q_hm, (const unsigned short*)k_hm, vt, ctxb, he);
    headsel<<<1, 64, 0, stream>>>(he, mask);
    gemm_obf<<<dim3(8, 32), 256, 0, stream>>>(ctxb, owb, ob, out, mask);
}

// Round 8
// 378.388 us; speedup vs baseline: 1.3425x; 1.0428x over previous
//
#include <hip/hip_runtime.h>
#include <math.h>

#define D_MODEL 1024
#define T_SEQ   1024
#define BATCH   4
#define NHEAD   16
#define HDIM    64

// keep counts: trunc(linspace(0.35,0.15,16)*64), min 1
__constant__ int KEEPC[16] = {22,21,20,19,18,18,17,16,15,14,13,13,12,11,10,9};

typedef short bh8  __attribute__((ext_vector_type(8)));
typedef float f32x4 __attribute__((ext_vector_type(4)));
typedef int   i32x4 __attribute__((ext_vector_type(4)));

__device__ __forceinline__ unsigned short f2bf(float f) {
    unsigned int u = __float_as_uint(f);
    return (unsigned short)((u + 0x7FFFu + ((u >> 16) & 1u)) >> 16);
}
__device__ __forceinline__ float bf2f(unsigned short h) {
    return __uint_as_float(((unsigned int)h) << 16);
}

// ---------------------------------------------------------------------------
// Cast weights once: kw -> (hi,lo) bf16 split; vw, ow -> single bf16.
// ---------------------------------------------------------------------------
__global__ void cast_weights(const float* __restrict__ kw,
                             unsigned short* __restrict__ kwh,
                             unsigned short* __restrict__ kwl,
                             const float* __restrict__ vw,
                             unsigned short* __restrict__ vwb,
                             const float* __restrict__ ow,
                             unsigned short* __restrict__ owb)
{
    const int NS = (D_MODEL * D_MODEL) / 8;
    int i = blockIdx.x * 256 + threadIdx.x;
    const float* src; unsigned short* dh; unsigned short* dl = nullptr;
    long off;
    if (i < NS)           { src = kw; dh = kwh; dl = kwl; off = i; }
    else if (i < 2 * NS)  { src = vw; dh = vwb; off = i - NS; }
    else if (i < 3 * NS)  { src = ow; dh = owb; off = i - 2 * NS; }
    else return;
    long e = off * 8;
    alignas(16) float fl[8];
    *(float4*)&fl[0] = *(const float4*)(src + e);
    *(float4*)&fl[4] = *(const float4*)(src + e + 4);
    uint4 hp, lp;
    unsigned int* hpw = (unsigned int*)&hp;
    unsigned int* lpw = (unsigned int*)&lp;
    #pragma unroll
    for (int c = 0; c < 4; c++) {
        unsigned short h0 = f2bf(fl[2 * c]), h1 = f2bf(fl[2 * c + 1]);
        hpw[c] = (unsigned int)h0 | ((unsigned int)h1 << 16);
        if (dl) {
            unsigned short l0 = f2bf(fl[2 * c] - bf2f(h0));
            unsigned short l1 = f2bf(fl[2 * c + 1] - bf2f(h1));
            lpw[c] = (unsigned int)l0 | ((unsigned int)l1 << 16);
        }
    }
    *(uint4*)(dh + e) = hp;
    if (dl) *(uint4*)(dl + e) = lp;
}

// ---------------------------------------------------------------------------
// prep_q: x -> 4 signed base-256 digit planes of n = rint(x * 2^23)
// (exact), and qw -> sign int8.
// ---------------------------------------------------------------------------
__global__ void prep_q(const float* __restrict__ x, signed char* __restrict__ dig,
                       const float* __restrict__ qw, signed char* __restrict__ sg)
{
    const int NX = (BATCH * T_SEQ * D_MODEL) / 8;   // 524288
    const int NW = (D_MODEL * D_MODEL) / 8;         // 131072
    const long PL = (long)BATCH * T_SEQ * D_MODEL;  // plane stride 4194304
    int i = blockIdx.x * 256 + threadIdx.x;
    if (i < NX) {
        long e = (long)i * 8;
        alignas(16) float f[8];
        *(float4*)&f[0] = *(const float4*)(x + e);
        *(float4*)&f[4] = *(const float4*)(x + e + 4);
        signed char d[4][8];
        #pragma unroll
        for (int c = 0; c < 8; c++) {
            int n = (int)rintf(f[c] * 8388608.0f);
            int d0 = (signed char)(n & 0xff); n = (n - d0) >> 8;
            int d1 = (signed char)(n & 0xff); n = (n - d1) >> 8;
            int d2 = (signed char)(n & 0xff); n = (n - d2) >> 8;
            d[0][c] = (signed char)d0; d[1][c] = (signed char)d1;
            d[2][c] = (signed char)d2; d[3][c] = (signed char)n;
        }
        #pragma unroll
        for (int p = 0; p < 4; p++)
            *(uint2*)(dig + p * PL + e) = *(uint2*)&d[p][0];
    } else if (i < NX + NW) {
        long e = (long)(i - NX) * 8;
        alignas(16) float f[8];
        *(float4*)&f[0] = *(const float4*)(qw + e);
        *(float4*)&f[4] = *(const float4*)(qw + e + 4);
        signed char s[8];
        #pragma unroll
        for (int c = 0; c < 8; c++)
            s[c] = (signed char)((f[c] > 0.f) - (f[c] < 0.f));
        *(uint2*)(sg + e) = *(uint2*)&s[0];
    }
}

// ---------------------------------------------------------------------------
// Q projection via EXACT int8 MFMA: q = 2^-23 * sum_p 256^p (Dp @ S^T) + b.
// Output fp32 HEAD-MAJOR: [(b*16+h)*1024 + t][d].
// 1-D grid of 1024, XCD-swizzled: all 16 bn-blocks of a bm share blk%8
// (same XCD under round-robin) so the A digit-slab is fetched once per XCD.
// ---------------------------------------------------------------------------
#define QST 80

__global__ __launch_bounds__(256, 2) void gemm_q_i8(
    const signed char* __restrict__ dig, const signed char* __restrict__ sg,
    const float* __restrict__ Bi, float* __restrict__ Y)
{
    __shared__ signed char Ad[4][64 * QST];
    __shared__ signed char Bs[64 * QST];

    const long PL = (long)BATCH * T_SEQ * D_MODEL;
    int tid  = threadIdx.x;
    int blk  = blockIdx.x;
    int low  = blk & 7, rest = blk >> 3;
    int bn   = (rest & 15) * 64;
    int bm   = (((rest >> 4) << 3) + low) * 64;
    int wave = tid >> 6, lane = tid & 63;
    int l15  = lane & 15, rg = lane >> 4;
    int wm   = (wave >> 1) * 32, wn = (wave & 1) * 32;
    int srow = tid >> 2;
    int skof = (tid & 3) * 16;

    i32x4 acc[4][2][2];
    #pragma unroll
    for (int p = 0; p < 4; p++)
        #pragma unroll
        for (int i = 0; i < 2; i++)
            #pragma unroll
            for (int j = 0; j < 2; j++) acc[p][i][j] = (i32x4)0;

    const signed char* ap = dig + (size_t)(bm + srow) * D_MODEL + skof;
    const signed char* bp = sg + (size_t)(bn + srow) * D_MODEL + skof;

    for (int k0 = 0; k0 < D_MODEL; k0 += 64) {
        uint4 av[4], bv;
        #pragma unroll
        for (int p = 0; p < 4; p++) av[p] = *(const uint4*)(ap + p * PL);
        bv = *(const uint4*)(bp);
        ap += 64; bp += 64;

        __syncthreads();
        #pragma unroll
        for (int p = 0; p < 4; p++)
            *(uint4*)&Ad[p][srow * QST + skof] = av[p];
        *(uint4*)&Bs[srow * QST + skof] = bv;
        __syncthreads();

        i32x4 bf[2];
        #pragma unroll
        for (int j = 0; j < 2; j++)
            bf[j] = *(i32x4*)&Bs[(wn + j * 16 + l15) * QST + rg * 16];
        #pragma unroll
        for (int p = 0; p < 4; p++) {
            i32x4 af[2];
            #pragma unroll
            for (int i = 0; i < 2; i++)
                af[i] = *(i32x4*)&Ad[p][(wm + i * 16 + l15) * QST + rg * 16];
            #pragma unroll
            for (int i = 0; i < 2; i++)
                #pragma unroll
                for (int j = 0; j < 2; j++)
                    acc[p][i][j] = __builtin_amdgcn_mfma_i32_16x16x64_i8(
                        af[i], bf[j], acc[p][i][j], 0, 0, 0);
        }
    }

    int hh = bn >> 6;
    #pragma unroll
    for (int j = 0; j < 2; j++) {
        int col = bn + wn + j * 16 + l15;
        int dd = col & 63;
        float bvv = Bi[col];
        #pragma unroll
        for (int i = 0; i < 2; i++) {
            #pragma unroll
            for (int r = 0; r < 4; r++) {
                int row = bm + wm + i * 16 + rg * 4 + r;
                int bb = row >> 10, tt = row & 1023;
                long t = (long)acc[0][i][j][r]
                       + ((long)acc[1][i][j][r] << 8)
                       + ((long)acc[2][i][j][r] << 16)
                       + ((long)acc[3][i][j][r] << 24);
                float o = (float)((double)t * (1.0 / 8388608.0)) + bvv;
                Y[(((size_t)(bb * NHEAD + hh)) * T_SEQ + tt) * HDIM + dd] = o;
            }
        }
    }
}

// ---------------------------------------------------------------------------
// MFMA GEMM, bf16 split of fp32 A on the fly. 1-D grid 256, XCD-swizzled
// (all 8 bn-blocks of a bm share blk%8 -> A-slab fetched once per XCD).
// split=1 (k-proj): 3-pass hi/lo product, fp32 out HEAD-MAJOR into Yf.
// split=0 (v-proj): single bf16 pass, bf16 out TRANSPOSED head-major Yv.
// ---------------------------------------------------------------------------
#define GLDK 72

__global__ __launch_bounds__(256, 2) void gemm_xsplit(
    const float* __restrict__ A, const unsigned short* __restrict__ Wh,
    const unsigned short* __restrict__ Wl, const float* __restrict__ Bi,
    float* __restrict__ Yf, unsigned short* __restrict__ Yv, int split)
{
    __shared__ unsigned short Ah[128 * GLDK];
    __shared__ unsigned short Al[128 * GLDK];
    __shared__ unsigned short Whs[128 * GLDK];
    __shared__ unsigned short Wls[128 * GLDK];

    int tid  = threadIdx.x;
    int blk  = blockIdx.x;
    int low  = blk & 7, rest = blk >> 3;
    int bn   = (rest & 7) * 128;
    int bm   = (((rest >> 3) << 3) + low) * 128;
    int wave = tid >> 6, lane = tid & 63;
    int l15  = lane & 15, q4 = lane >> 4;
    int wm   = (wave >> 1) * 64, wn = (wave & 1) * 64;
    int srow = tid >> 1;
    int scol = (tid & 1) * 32;

    f32x4 acc[4][4];
    #pragma unroll
    for (int i = 0; i < 4; i++)
        #pragma unroll
        for (int j = 0; j < 4; j++) acc[i][j] = (f32x4)0.f;

    const float* ap = A + (size_t)(bm + srow) * D_MODEL + scol;
    const unsigned short* whp = Wh + (size_t)(bn + srow) * D_MODEL + scol;
    const unsigned short* wlp = (split ? Wl : Wh) + (size_t)(bn + srow) * D_MODEL + scol;

    for (int k0 = 0; k0 < D_MODEL; k0 += 64) {
        alignas(16) float fl[32];
        #pragma unroll
        for (int c = 0; c < 8; c++) *(float4*)&fl[4 * c] = *(const float4*)(ap + 4 * c);
        uint4 w0 = *(const uint4*)(whp + 0),  w1 = *(const uint4*)(whp + 8);
        uint4 w2 = *(const uint4*)(whp + 16), w3 = *(const uint4*)(whp + 24);
        uint4 x0, x1, x2, x3;
        if (split) {
            x0 = *(const uint4*)(wlp + 0);  x1 = *(const uint4*)(wlp + 8);
            x2 = *(const uint4*)(wlp + 16); x3 = *(const uint4*)(wlp + 24);
        }
        ap += 64; whp += 64; wlp += 64;

        unsigned int hw[16], lw[16];
        #pragma unroll
        for (int c = 0; c < 16; c++) {
            unsigned short h0 = f2bf(fl[2 * c]), h1 = f2bf(fl[2 * c + 1]);
            hw[c] = (unsigned int)h0 | ((unsigned int)h1 << 16);
            if (split) {
                unsigned short l0 = f2bf(fl[2 * c] - bf2f(h0));
                unsigned short l1 = f2bf(fl[2 * c + 1] - bf2f(h1));
                lw[c] = (unsigned int)l0 | ((unsigned int)l1 << 16);
            }
        }

        __syncthreads();
        unsigned int* ah = (unsigned int*)&Ah[srow * GLDK + scol];
        #pragma unroll
        for (int g = 0; g < 4; g++)
            *(uint4*)(ah + 4 * g) = make_uint4(hw[4 * g], hw[4 * g + 1], hw[4 * g + 2], hw[4 * g + 3]);
        if (split) {
            unsigned int* al = (unsigned int*)&Al[srow * GLDK + scol];
            #pragma unroll
            for (int g = 0; g < 4; g++)
                *(uint4*)(al + 4 * g) = make_uint4(lw[4 * g], lw[4 * g + 1], lw[4 * g + 2], lw[4 * g + 3]);
        }
        unsigned short* ws = &Whs[srow * GLDK + scol];
        *(uint4*)(ws + 0) = w0; *(uint4*)(ws + 8)  = w1;
        *(uint4*)(ws + 16) = w2; *(uint4*)(ws + 24) = w3;
        if (split) {
            unsigned short* wl2 = &Wls[srow * GLDK + scol];
            *(uint4*)(wl2 + 0) = x0; *(uint4*)(wl2 + 8)  = x1;
            *(uint4*)(wl2 + 16) = x2; *(uint4*)(wl2 + 24) = x3;
        }
        __syncthreads();

        #pragma unroll
        for (int kc = 0; kc < 64; kc += 32) {
            bh8 ahf[4], whf[4];
            #pragma unroll
            for (int i = 0; i < 4; i++)
                ahf[i] = *(bh8*)&Ah[(wm + i * 16 + l15) * GLDK + kc + q4 * 8];
            #pragma unroll
            for (int j = 0; j < 4; j++)
                whf[j] = *(bh8*)&Whs[(wn + j * 16 + l15) * GLDK + kc + q4 * 8];
            #pragma unroll
            for (int i = 0; i < 4; i++)
                #pragma unroll
                for (int j = 0; j < 4; j++)
                    acc[i][j] = __builtin_amdgcn_mfma_f32_16x16x32_bf16(ahf[i], whf[j], acc[i][j], 0, 0, 0);
            if (split) {
                bh8 alf[4], wlf[4];
                #pragma unroll
                for (int i = 0; i < 4; i++)
                    alf[i] = *(bh8*)&Al[(wm + i * 16 + l15) * GLDK + kc + q4 * 8];
                #pragma unroll
                for (int j = 0; j < 4; j++)
                    wlf[j] = *(bh8*)&Wls[(wn + j * 16 + l15) * GLDK + kc + q4 * 8];
                #pragma unroll
                for (int i = 0; i < 4; i++)
                    #pragma unroll
                    for (int j = 0; j < 4; j++) {
                        acc[i][j] = __builtin_amdgcn_mfma_f32_16x16x32_bf16(ahf[i], wlf[j], acc[i][j], 0, 0, 0);
                        acc[i][j] = __builtin_amdgcn_mfma_f32_16x16x32_bf16(alf[i], whf[j], acc[i][j], 0, 0, 0);
                    }
            }
        }
    }

    #pragma unroll
    for (int j = 0; j < 4; j++) {
        int col = bn + wn + j * 16 + l15;
        int hh = col >> 6, dd = col & 63;
        float bv = Bi[col];
        #pragma unroll
        for (int i = 0; i < 4; i++) {
            int row0 = bm + wm + i * 16 + q4 * 4;
            int bb = row0 >> 10, tt = row0 & 1023;
            if (split) {
                float* yp = Yf + (((size_t)(bb * NHEAD + hh)) * T_SEQ + tt) * HDIM + dd;
                #pragma unroll
                for (int r = 0; r < 4; r++)
                    yp[(size_t)r * HDIM] = acc[i][j][r] + bv;
            } else {
                uint2 u;
                u.x = (unsigned int)f2bf(acc[i][j][0] + bv) | ((unsigned int)f2bf(acc[i][j][1] + bv) << 16);
                u.y = (unsigned int)f2bf(acc[i][j][2] + bv) | ((unsigned int)f2bf(acc[i][j][3] + bv) << 16);
                *(uint2*)(Yv + ((size_t)(bb * NHEAD + hh) * HDIM + dd) * T_SEQ + tt) = u;
            }
        }
    }
}

// ---------------------------------------------------------------------------
// Out-projection: bf16 ctx (model-major) @ bf16 W^T + bias, head mask on A.
// 1-D grid 256, XCD-swizzled like gemm_xsplit.
// ---------------------------------------------------------------------------
__global__ __launch_bounds__(256, 2) void gemm_obf(
    const unsigned short* __restrict__ A, const unsigned short* __restrict__ W,
    const float* __restrict__ Bi, float* __restrict__ Y,
    const float* __restrict__ amask)
{
    __shared__ unsigned short As[128 * GLDK];
    __shared__ unsigned short Ws[128 * GLDK];

    int tid  = threadIdx.x;
    int blk  = blockIdx.x;
    int low  = blk & 7, rest = blk >> 3;
    int bn   = (rest & 7) * 128;
    int bm   = (((rest >> 3) << 3) + low) * 128;
    int wave = tid >> 6, lane = tid & 63;
    int l15  = lane & 15, q4 = lane >> 4;
    int wm   = (wave >> 1) * 64, wn = (wave & 1) * 64;
    int srow = tid >> 1;
    int scol = (tid & 1) * 32;
    int batch = bm >> 10;

    f32x4 acc[4][4];
    #pragma unroll
    for (int i = 0; i < 4; i++)
        #pragma unroll
        for (int j = 0; j < 4; j++) acc[i][j] = (f32x4)0.f;

    const unsigned short* ap = A + (size_t)(bm + srow) * D_MODEL + scol;
    const unsigned short* wp = W + (size_t)(bn + srow) * D_MODEL + scol;

    for (int k0 = 0; k0 < D_MODEL; k0 += 64) {
        uint4 a0 = *(const uint4*)(ap + 0),  a1 = *(const uint4*)(ap + 8);
        uint4 a2 = *(const uint4*)(ap + 16), a3 = *(const uint4*)(ap + 24);
        uint4 w0 = *(const uint4*)(wp + 0),  w1 = *(const uint4*)(wp + 8);
        uint4 w2 = *(const uint4*)(wp + 16), w3 = *(const uint4*)(wp + 24);
        ap += 64; wp += 64;
        if (amask[batch * NHEAD + (k0 >> 6)] == 0.f) {
            a0 = a1 = a2 = a3 = make_uint4(0, 0, 0, 0);
        }
        __syncthreads();
        unsigned short* as = &As[srow * GLDK + scol];
        *(uint4*)(as + 0) = a0; *(uint4*)(as + 8)  = a1;
        *(uint4*)(as + 16) = a2; *(uint4*)(as + 24) = a3;
        unsigned short* ws = &Ws[srow * GLDK + scol];
        *(uint4*)(ws + 0) = w0; *(uint4*)(ws + 8)  = w1;
        *(uint4*)(ws + 16) = w2; *(uint4*)(ws + 24) = w3;
        __syncthreads();

        #pragma unroll
        for (int kc = 0; kc < 64; kc += 32) {
            bh8 af[4], wf[4];
            #pragma unroll
            for (int i = 0; i < 4; i++)
                af[i] = *(bh8*)&As[(wm + i * 16 + l15) * GLDK + kc + q4 * 8];
            #pragma unroll
            for (int j = 0; j < 4; j++)
                wf[j] = *(bh8*)&Ws[(wn + j * 16 + l15) * GLDK + kc + q4 * 8];
            #pragma unroll
            for (int i = 0; i < 4; i++)
                #pragma unroll
                for (int j = 0; j < 4; j++)
                    acc[i][j] = __builtin_amdgcn_mfma_f32_16x16x32_bf16(af[i], wf[j], acc[i][j], 0, 0, 0);
        }
    }

    #pragma unroll
    for (int j = 0; j < 4; j++) {
        int col = bn + wn + j * 16 + l15;
        float bv = Bi[col];
        #pragma unroll
        for (int i = 0; i < 4; i++) {
            int row = bm + wm + i * 16 + q4 * 4;
            #pragma unroll
            for (int r = 0; r < 4; r++)
                Y[(size_t)(row + r) * D_MODEL + col] = acc[i][j][r] + bv;
        }
    }
}

// ---------------------------------------------------------------------------
// normqk: RMS-norm 64-elem rows (head-major fp32) and rewrite IN PLACE as
// row-interleaved bf16 hi/lo (row r: 64 hi shorts then 64 lo shorts).
// q (y==0) additionally gets exact top-k via ballot binary search.
// ---------------------------------------------------------------------------
__global__ void normqk(float* __restrict__ Q, float* __restrict__ Kb)
{
    int tid  = threadIdx.x;
    int wid  = tid >> 6;
    int lane = tid & 63;
    long rid = (long)blockIdx.x * 4 + wid;   // [(b*16+h)*1024 + t]
    int isK  = blockIdx.y;
    int h    = (int)((rid >> 10) & 15);

    float* p = (isK ? Kb : Q) + rid * HDIM;
    float x = p[lane];
    float ss = x * x;
    #pragma unroll
    for (int off = 32; off > 0; off >>= 1) ss += __shfl_xor(ss, off);
    float rms = sqrtf(ss * (1.0f / 64.0f));
    float xn = x / (rms + 1e-6f);

    if (!isK) {
        unsigned int ai = __float_as_uint(fabsf(xn));
        unsigned int t = 0;
        int keep = KEEPC[h];
        #pragma unroll
        for (int bit = 30; bit >= 0; --bit) {
            unsigned int cand = t | (1u << bit);
            unsigned long long b = __ballot(ai >= cand);
            if (__popcll(b) >= keep) t = cand;
        }
        if (ai < t) xn = 0.f;   // keep iff |x| >= (keep-th largest)
    }

    unsigned short hi = f2bf(xn);
    unsigned short lo = f2bf(xn - bf2f(hi));
    unsigned short* ps = (unsigned short*)p;
    ps[lane]      = hi;
    ps[64 + lane] = lo;
}

// ---------------------------------------------------------------------------
// MFMA flash attention, transposed S + cooperative LDS staging.
// 1-D grid 1024, XCD-swizzled: all 16 qt-blocks of one (b,h) share blk%8
// so each head's K/V slab is fetched once per XCD (3 MB/XCD working set).
// S^T = K·Q^T; per-lane online softmax (2 shfls); per-wave P slab;
// O^T = V^T·P^T. Emits ctx bf16 and sum(attn^2) per head (f64 atomics).
// ---------------------------------------------------------------------------
#define KST 72   // LDS row stride in shorts (144 B; 2-way bank alias = free)

__global__ __launch_bounds__(256, 4) void attn_kernel(
    const unsigned short* __restrict__ Qsg,   // [row][128] = 64 hi | 64 lo
    const unsigned short* __restrict__ Ksg,
    const unsigned short* __restrict__ Vtg,   // [(bh)*64+d][1024] bf16
    unsigned short* __restrict__ Ctx, double* __restrict__ He)
{
    __shared__ unsigned short Kh[64 * KST];
    __shared__ unsigned short Kl[64 * KST];
    __shared__ unsigned short Vt[64 * KST];
    __shared__ unsigned short Ps[4][16 * KST];

    int tid = threadIdx.x;
    int blk = blockIdx.x;
    int low = blk & 7, rest = blk >> 3;
    int qt  = 15 - (rest & 15);               // heavy blocks first
    int r2  = rest >> 4;                      // 0..7
    int h   = (r2 & 1) * 8 + low;
    int b   = r2 >> 1;
    int bh = b * NHEAD + h;
    size_t rbase = (size_t)bh * T_SEQ;

    int wave = tid >> 6, lane = tid & 63;
    int l15 = lane & 15, rg = lane >> 4;
    int srow = tid >> 2;                      // staging row 0..63
    int scol = (tid & 3) * 16;                // staging col offset (shorts)

    int qrow = qt * 64 + wave * 16 + l15;     // this lane's query t-index

    // hoisted Q B-fragments (hi/lo x kc) — loaded once from global
    bh8 qf[2][2];
    {
        const unsigned short* qp = Qsg + (rbase + qrow) * 128 + rg * 8;
        qf[0][0] = *(const bh8*)(qp);
        qf[0][1] = *(const bh8*)(qp + 32);
        qf[1][0] = *(const bh8*)(qp + 64);
        qf[1][1] = *(const bh8*)(qp + 96);
    }

    float m = -1e30f, l = 0.f, s2 = 0.f;
    f32x4 o[4];
    #pragma unroll
    for (int n = 0; n < 4; n++) o[n] = (f32x4)0.f;

    unsigned short* myPs = &Ps[wave][0];
    const unsigned short* vbase = Vtg + (size_t)bh * HDIM * T_SEQ;

    for (int kt = 0; kt <= qt; ++kt) {
        // ---- cooperative staging (coalesced 16B loads)
        const unsigned short* krow = Ksg + (rbase + kt * 64 + srow) * 128;
        uint4 kh0 = *(const uint4*)(krow + scol);
        uint4 kh1 = *(const uint4*)(krow + scol + 8);
        uint4 kl0 = *(const uint4*)(krow + 64 + scol);
        uint4 kl1 = *(const uint4*)(krow + 64 + scol + 8);
        const unsigned short* vrow = vbase + (size_t)srow * T_SEQ + kt * 64 + scol;
        uint4 vv0 = *(const uint4*)(vrow);
        uint4 vv1 = *(const uint4*)(vrow + 8);

        __syncthreads();   // prior iteration's LDS reads done
        *(uint4*)&Kh[srow * KST + scol]     = kh0;
        *(uint4*)&Kh[srow * KST + scol + 8] = kh1;
        *(uint4*)&Kl[srow * KST + scol]     = kl0;
        *(uint4*)&Kl[srow * KST + scol + 8] = kl1;
        *(uint4*)&Vt[srow * KST + scol]     = vv0;
        *(uint4*)&Vt[srow * KST + scol + 8] = vv1;
        __syncthreads();

        // ---- S^T = K · Q^T  (split-bf16, 3 passes; A=K rows, B=Q rows)
        f32x4 s[4];
        #pragma unroll
        for (int n = 0; n < 4; n++) s[n] = (f32x4)0.f;
        #pragma unroll
        for (int n = 0; n < 4; n++) {
            const unsigned short* kr = &Kh[(n * 16 + l15) * KST + rg * 8];
            const unsigned short* lr = &Kl[(n * 16 + l15) * KST + rg * 8];
            bh8 ah0 = *(const bh8*)(kr);
            bh8 ah1 = *(const bh8*)(kr + 32);
            bh8 al0 = *(const bh8*)(lr);
            bh8 al1 = *(const bh8*)(lr + 32);
            s[n] = __builtin_amdgcn_mfma_f32_16x16x32_bf16(ah0, qf[0][0], s[n], 0, 0, 0);
            s[n] = __builtin_amdgcn_mfma_f32_16x16x32_bf16(ah1, qf[0][1], s[n], 0, 0, 0);
            s[n] = __builtin_amdgcn_mfma_f32_16x16x32_bf16(ah0, qf[1][0], s[n], 0, 0, 0);
            s[n] = __builtin_amdgcn_mfma_f32_16x16x32_bf16(ah1, qf[1][1], s[n], 0, 0, 0);
            s[n] = __builtin_amdgcn_mfma_f32_16x16x32_bf16(al0, qf[0][0], s[n], 0, 0, 0);
            s[n] = __builtin_amdgcn_mfma_f32_16x16x32_bf16(al1, qf[0][1], s[n], 0, 0, 0);
        }

        if (kt == qt) {   // causal: key (n*16+rg*4+e) > query (wave*16+l15)
            #pragma unroll
            for (int n = 0; n < 4; n++)
                #pragma unroll
                for (int e = 0; e < 4; e++)
                    if (n * 16 + rg * 4 + e > wave * 16 + l15) s[n][e] = -1e30f;
        }

        // ---- online softmax: 16 in-lane keys + 2 shfls across quads
        float mx = -1e30f;
        #pragma unroll
        for (int n = 0; n < 4; n++)
            #pragma unroll
            for (int e = 0; e < 4; e++) mx = fmaxf(mx, s[n][e]);
        mx = fmaxf(mx, __shfl_xor(mx, 16));
        mx = fmaxf(mx, __shfl_xor(mx, 32));
        float mn = fmaxf(m, mx);
        float alpha = __expf(m - mn);
        m = mn;
        float rs = 0.f, rs2 = 0.f;
        #pragma unroll
        for (int n = 0; n < 4; n++)
            #pragma unroll
            for (int e = 0; e < 4; e++) {
                float pv = __expf(s[n][e] - mn);
                s[n][e] = pv;
                rs += pv; rs2 += pv * pv;
            }
        rs  += __shfl_xor(rs, 16);  rs  += __shfl_xor(rs, 32);
        rs2 += __shfl_xor(rs2, 16); rs2 += __shfl_xor(rs2, 32);
        l  = l * alpha + rs;
        s2 = s2 * alpha * alpha + rs2;

        // ---- P^T round-trip through per-wave LDS slab (rows = queries)
        #pragma unroll
        for (int n = 0; n < 4; n++) {
            uint2 u;
            u.x = (unsigned int)f2bf(s[n][0]) | ((unsigned int)f2bf(s[n][1]) << 16);
            u.y = (unsigned int)f2bf(s[n][2]) | ((unsigned int)f2bf(s[n][3]) << 16);
            *(uint2*)&myPs[l15 * KST + n * 16 + rg * 4] = u;
        }
        bh8 pf0 = *(bh8*)&myPs[l15 * KST + rg * 8];
        bh8 pf1 = *(bh8*)&myPs[l15 * KST + 32 + rg * 8];

        // ---- O^T = V^T · P^T  (rescale first; alpha is per-lane scalar)
        #pragma unroll
        for (int n = 0; n < 4; n++) {
            o[n] *= alpha;
            const unsigned short* vr = &Vt[(n * 16 + l15) * KST + rg * 8];
            bh8 v0 = *(const bh8*)(vr);
            bh8 v1 = *(const bh8*)(vr + 32);
            o[n] = __builtin_amdgcn_mfma_f32_16x16x32_bf16(v0, pf0, o[n], 0, 0, 0);
            o[n] = __builtin_amdgcn_mfma_f32_16x16x32_bf16(v1, pf1, o[n], 0, 0, 0);
        }
    }

    float linv = 1.f / l;
    float en = (rg == 0) ? s2 * linv * linv : 0.f;
    en += __shfl_xor(en, 1); en += __shfl_xor(en, 2);
    en += __shfl_xor(en, 4); en += __shfl_xor(en, 8);
    if (lane == 0) atomicAdd(&He[bh], (double)en);

    // ctx (model-major bf16): lane owns query qrow, d = n*16 + rg*4 + e
    unsigned short* cp = Ctx + ((size_t)b * T_SEQ + qrow) * D_MODEL + h * HDIM;
    #pragma unroll
    for (int n = 0; n < 4; n++) {
        uint2 u;
        u.x = (unsigned int)f2bf(o[n][0] * linv) | ((unsigned int)f2bf(o[n][1] * linv) << 16);
        u.y = (unsigned int)f2bf(o[n][2] * linv) | ((unsigned int)f2bf(o[n][3] * linv) << 16);
        *(uint2*)(cp + n * 16 + rg * 4) = u;
    }
}

// ---------------------------------------------------------------------------
// Per-batch head selection (unchanged).
// ---------------------------------------------------------------------------
__global__ void headsel(const double* __restrict__ He, float* __restrict__ Mask)
{
    int b = threadIdx.x;
    if (b >= BATCH) return;
    double e[NHEAD];
    double mx = -1e300;
    for (int h = 0; h < NHEAD; h++) {
        e[h] = He[b * NHEAD + h] / (1024.0 * 1024.0);
        mx = fmax(mx, e[h]);
    }
    double p[NHEAD], s = 0.0;
    for (int h = 0; h < NHEAD; h++) { p[h] = exp(e[h] - mx); s += p[h]; }
    double ent = 0.0;
    for (int h = 0; h < NHEAD; h++) {
        double ph = p[h] / s;
        ent -= ph * log(ph + 1e-9);
    }
    double entn = ent / log(16.0);
    entn = fmin(fmax(entn, 0.0), 1.0);
    int keep = (int)rint(2.0 + entn * 4.0);
    if (keep < 1) keep = 1;
    if (keep > NHEAD) keep = NHEAD;
    double srt[NHEAD];
    for (int h = 0; h < NHEAD; h++) srt[h] = e[h];
    for (int i = 1; i < NHEAD; i++) {
        double v = srt[i]; int j = i - 1;
        while (j >= 0 && srt[j] < v) { srt[j + 1] = srt[j]; j--; }
        srt[j + 1] = v;
    }
    double th = srt[keep - 1];
    for (int h = 0; h < NHEAD; h++)
        Mask[b * NHEAD + h] = (e[h] >= th) ? 1.0f : 0.0f;
}

// ---------------------------------------------------------------------------
extern "C" void kernel_launch(void* const* d_in, const int* in_sizes, int n_in,
                              void* d_out, int out_size, void* d_ws, size_t ws_size,
                              hipStream_t stream)
{
    (void)in_sizes; (void)n_in; (void)out_size; (void)ws_size;
    const float* x  = (const float*)d_in[0];
    const float* qw = (const float*)d_in[1];
    const float* qb = (const float*)d_in[2];
    const float* kw = (const float*)d_in[3];
    const float* kb = (const float*)d_in[4];
    const float* vw = (const float*)d_in[5];
    const float* vb = (const float*)d_in[6];
    const float* ow = (const float*)d_in[7];
    const float* ob = (const float*)d_in[8];
    float* out = (float*)d_out;

    char* base = (char*)d_ws;
    const size_t MB = (size_t)1024 * 1024;
    float*          q_hm = (float*)(base);                    // 16 MB head-major
    float*          k_hm = (float*)(base + 16 * MB);          // 16 MB head-major
    unsigned short* vt   = (unsigned short*)(base + 32 * MB); // 8 MB V^T bf16
    unsigned short* ctxb = (unsigned short*)(base + 40 * MB); // 8 MB bf16
    unsigned short* kwh  = (unsigned short*)(base + 48 * MB); // 2 MB
    unsigned short* kwl  = (unsigned short*)(base + 50 * MB);
    unsigned short* vwb  = (unsigned short*)(base + 52 * MB);
    unsigned short* owb  = (unsigned short*)(base + 54 * MB);
    double*         he   = (double*)(base + 56 * MB);
    float*          mask = (float*)(base + 56 * MB + 512);
    signed char*    dig  = (signed char*)(base + 32 * MB);    // 16 MB (overlaid)
    signed char*    sg   = (signed char*)(base + 57 * MB);    // 1 MB

    hipMemsetAsync(he, 0, 64 * sizeof(double), stream);

    cast_weights<<<1536, 256, 0, stream>>>(kw, kwh, kwl, vw, vwb, ow, owb);
    prep_q<<<2560, 256, 0, stream>>>(x, dig, qw, sg);
    // q projection: exact int8-digit MFMA (consumes dig before vt overlay)
    gemm_q_i8<<<1024, 256, 0, stream>>>(dig, sg, qb, q_hm);
    // k projection: split-bf16 MFMA, fp32 head-major out
    gemm_xsplit<<<256, 256, 0, stream>>>(x, kwh, kwl, kb, k_hm, nullptr, 1);
    // v projection: bf16 MFMA, V^T bf16 out
    gemm_xsplit<<<256, 256, 0, stream>>>(x, vwb, nullptr, vb, nullptr, vt, 0);
    // norm + top-k, rewrite q/k in place as interleaved bf16 hi/lo splits
    normqk<<<dim3(16384, 2), 256, 0, stream>>>(q_hm, k_hm);
    attn_kernel<<<1024, 256, 0, stream>>>(
        (const unsigned short*)q_hm, (const unsigned short*)k_hm, vt, ctxb, he);
    headsel<<<1, 64, 0, stream>>>(he, mask);
    gemm_obf<<<256, 256, 0, stream>>>(ctxb, owb, ob, out, mask);
}

// Round 10
// 338.831 us; speedup vs baseline: 1.4992x; 1.1167x over previous
//
#include <hip/hip_runtime.h>
#include <math.h>

#define D_MODEL 1024
#define T_SEQ   1024
#define BATCH   4
#define NHEAD   16
#define HDIM    64

// keep counts: trunc(linspace(0.35,0.15,16)*64), min 1
__constant__ int KEEPC[16] = {22,21,20,19,18,18,17,16,15,14,13,13,12,11,10,9};

typedef short bh8  __attribute__((ext_vector_type(8)));
typedef float f32x4 __attribute__((ext_vector_type(4)));
typedef int   i32x4 __attribute__((ext_vector_type(4)));

__device__ __forceinline__ unsigned short f2bf(float f) {
    unsigned int u = __float_as_uint(f);
    return (unsigned short)((u + 0x7FFFu + ((u >> 16) & 1u)) >> 16);
}
__device__ __forceinline__ float bf2f(unsigned short h) {
    return __uint_as_float(((unsigned int)h) << 16);
}

// ---------------------------------------------------------------------------
// cast_prep (merged cast_weights + prep_q):
//  kw -> (hi,lo) bf16; vw, ow -> bf16; x -> 4 base-256 digit planes of
//  n = rint(x*2^23) (exact); qw -> sign int8.
// ---------------------------------------------------------------------------
__global__ void cast_prep(const float* __restrict__ kw,
                          unsigned short* __restrict__ kwh,
                          unsigned short* __restrict__ kwl,
                          const float* __restrict__ vw,
                          unsigned short* __restrict__ vwb,
                          const float* __restrict__ ow,
                          unsigned short* __restrict__ owb,
                          const float* __restrict__ x,
                          signed char* __restrict__ dig,
                          const float* __restrict__ qw,
                          signed char* __restrict__ sg)
{
    const int NS = (D_MODEL * D_MODEL) / 8;          // 131072
    const int NX = (BATCH * T_SEQ * D_MODEL) / 8;    // 524288
    const long PL = (long)BATCH * T_SEQ * D_MODEL;   // 4194304
    int i = blockIdx.x * 256 + threadIdx.x;

    if (i < 3 * NS) {
        const float* src; unsigned short* dh; unsigned short* dl = nullptr;
        long off;
        if (i < NS)          { src = kw; dh = kwh; dl = kwl; off = i; }
        else if (i < 2 * NS) { src = vw; dh = vwb; off = i - NS; }
        else                 { src = ow; dh = owb; off = i - 2 * NS; }
        long e = off * 8;
        alignas(16) float fl[8];
        *(float4*)&fl[0] = *(const float4*)(src + e);
        *(float4*)&fl[4] = *(const float4*)(src + e + 4);
        uint4 hp, lp;
        unsigned int* hpw = (unsigned int*)&hp;
        unsigned int* lpw = (unsigned int*)&lp;
        #pragma unroll
        for (int c = 0; c < 4; c++) {
            unsigned short h0 = f2bf(fl[2 * c]), h1 = f2bf(fl[2 * c + 1]);
            hpw[c] = (unsigned int)h0 | ((unsigned int)h1 << 16);
            if (dl) {
                unsigned short l0 = f2bf(fl[2 * c] - bf2f(h0));
                unsigned short l1 = f2bf(fl[2 * c + 1] - bf2f(h1));
                lpw[c] = (unsigned int)l0 | ((unsigned int)l1 << 16);
            }
        }
        *(uint4*)(dh + e) = hp;
        if (dl) *(uint4*)(dl + e) = lp;
    } else if (i < 3 * NS + NX) {
        long e = (long)(i - 3 * NS) * 8;
        alignas(16) float f[8];
        *(float4*)&f[0] = *(const float4*)(x + e);
        *(float4*)&f[4] = *(const float4*)(x + e + 4);
        signed char d[4][8];
        #pragma unroll
        for (int c = 0; c < 8; c++) {
            int n = (int)rintf(f[c] * 8388608.0f);
            int d0 = (signed char)(n & 0xff); n = (n - d0) >> 8;
            int d1 = (signed char)(n & 0xff); n = (n - d1) >> 8;
            int d2 = (signed char)(n & 0xff); n = (n - d2) >> 8;
            d[0][c] = (signed char)d0; d[1][c] = (signed char)d1;
            d[2][c] = (signed char)d2; d[3][c] = (signed char)n;
        }
        #pragma unroll
        for (int p = 0; p < 4; p++)
            *(uint2*)(dig + p * PL + e) = *(uint2*)&d[p][0];
    } else if (i < 3 * NS + NX + NS) {
        long e = (long)(i - 3 * NS - NX) * 8;
        alignas(16) float f[8];
        *(float4*)&f[0] = *(const float4*)(qw + e);
        *(float4*)&f[4] = *(const float4*)(qw + e + 4);
        signed char s[8];
        #pragma unroll
        for (int c = 0; c < 8; c++)
            s[c] = (signed char)((f[c] > 0.f) - (f[c] < 0.f));
        *(uint2*)(sg + e) = *(uint2*)&s[0];
    }
}

// ---------------------------------------------------------------------------
// Q projection via EXACT int8 MFMA: q = 2^-23 * sum_p 256^p (Dp @ S^T) + b.
// Output fp32 HEAD-MAJOR: [(b*16+h)*1024 + t][d]. 1-D grid 1024,
// XCD-swizzled (bn varies within blk%8 class -> A-slab once per XCD).
// ---------------------------------------------------------------------------
#define QST 80

__global__ __launch_bounds__(256, 2) void gemm_q_i8(
    const signed char* __restrict__ dig, const signed char* __restrict__ sg,
    const float* __restrict__ Bi, float* __restrict__ Y)
{
    __shared__ signed char Ad[4][64 * QST];
    __shared__ signed char Bs[64 * QST];

    const long PL = (long)BATCH * T_SEQ * D_MODEL;
    int tid  = threadIdx.x;
    int blk  = blockIdx.x;
    int low  = blk & 7, rest = blk >> 3;
    int bn   = (rest & 15) * 64;
    int bm   = (((rest >> 4) << 3) + low) * 64;
    int wave = tid >> 6, lane = tid & 63;
    int l15  = lane & 15, rg = lane >> 4;
    int wm   = (wave >> 1) * 32, wn = (wave & 1) * 32;
    int srow = tid >> 2;
    int skof = (tid & 3) * 16;

    i32x4 acc[4][2][2];
    #pragma unroll
    for (int p = 0; p < 4; p++)
        #pragma unroll
        for (int i = 0; i < 2; i++)
            #pragma unroll
            for (int j = 0; j < 2; j++) acc[p][i][j] = (i32x4)0;

    const signed char* ap = dig + (size_t)(bm + srow) * D_MODEL + skof;
    const signed char* bp = sg + (size_t)(bn + srow) * D_MODEL + skof;

    for (int k0 = 0; k0 < D_MODEL; k0 += 64) {
        uint4 av[4], bv;
        #pragma unroll
        for (int p = 0; p < 4; p++) av[p] = *(const uint4*)(ap + p * PL);
        bv = *(const uint4*)(bp);
        ap += 64; bp += 64;

        __syncthreads();
        #pragma unroll
        for (int p = 0; p < 4; p++)
            *(uint4*)&Ad[p][srow * QST + skof] = av[p];
        *(uint4*)&Bs[srow * QST + skof] = bv;
        __syncthreads();

        i32x4 bf[2];
        #pragma unroll
        for (int j = 0; j < 2; j++)
            bf[j] = *(i32x4*)&Bs[(wn + j * 16 + l15) * QST + rg * 16];
        #pragma unroll
        for (int p = 0; p < 4; p++) {
            i32x4 af[2];
            #pragma unroll
            for (int i = 0; i < 2; i++)
                af[i] = *(i32x4*)&Ad[p][(wm + i * 16 + l15) * QST + rg * 16];
            #pragma unroll
            for (int i = 0; i < 2; i++)
                #pragma unroll
                for (int j = 0; j < 2; j++)
                    acc[p][i][j] = __builtin_amdgcn_mfma_i32_16x16x64_i8(
                        af[i], bf[j], acc[p][i][j], 0, 0, 0);
        }
    }

    int hh = bn >> 6;
    #pragma unroll
    for (int j = 0; j < 2; j++) {
        int col = bn + wn + j * 16 + l15;
        int dd = col & 63;
        float bvv = Bi[col];
        #pragma unroll
        for (int i = 0; i < 2; i++) {
            #pragma unroll
            for (int r = 0; r < 4; r++) {
                int row = bm + wm + i * 16 + rg * 4 + r;
                int bb = row >> 10, tt = row & 1023;
                long t = (long)acc[0][i][j][r]
                       + ((long)acc[1][i][j][r] << 8)
                       + ((long)acc[2][i][j][r] << 16)
                       + ((long)acc[3][i][j][r] << 24);
                float o = (float)((double)t * (1.0 / 8388608.0)) + bvv;
                Y[(((size_t)(bb * NHEAD + hh)) * T_SEQ + tt) * HDIM + dd] = o;
            }
        }
    }
}

// ---------------------------------------------------------------------------
// Merged K+V projection (grid 512: z=blk>>8, 0=k split-bf16, 1=v bf16).
// XCD-swizzled on the inner 256. bf16 split of fp32 A on the fly.
// k: 3-pass hi/lo product + FUSED RMS-norm epilogue -> norm-split bf16
//    hi|lo rows [(b*16+h)*1024+t][128]  (16 MB total — full allocation!).
// v: single bf16 pass, bf16 out TRANSPOSED head-major Yv[(bh)*64+d][t].
// ---------------------------------------------------------------------------
#define GLDK 72

__global__ __launch_bounds__(256, 2) void gemm_kv(
    const float* __restrict__ A,
    const unsigned short* __restrict__ kwh, const unsigned short* __restrict__ kwl,
    const float* __restrict__ kb,
    const unsigned short* __restrict__ vwb, const float* __restrict__ vb,
    unsigned short* __restrict__ Yk, unsigned short* __restrict__ Yv)
{
    __shared__ unsigned short Ah[128 * GLDK];
    __shared__ unsigned short Al[128 * GLDK];
    __shared__ unsigned short Whs[128 * GLDK];
    __shared__ unsigned short Wls[128 * GLDK];

    int tid  = threadIdx.x;
    int blk  = blockIdx.x;
    int z    = blk >> 8;               // 0 = k, 1 = v
    int split = (z == 0);
    int inner = blk & 255;
    int low  = inner & 7, rest = inner >> 3;
    int bn   = (rest & 7) * 128;
    int bm   = (((rest >> 3) << 3) + low) * 128;
    const unsigned short* Wh = split ? kwh : vwb;
    const unsigned short* Wl = split ? kwl : vwb;
    const float*          Bi = split ? kb : vb;

    int wave = tid >> 6, lane = tid & 63;
    int l15  = lane & 15, q4 = lane >> 4;
    int wm   = (wave >> 1) * 64, wn = (wave & 1) * 64;
    int srow = tid >> 1;
    int scol = (tid & 1) * 32;

    f32x4 acc[4][4];
    #pragma unroll
    for (int i = 0; i < 4; i++)
        #pragma unroll
        for (int j = 0; j < 4; j++) acc[i][j] = (f32x4)0.f;

    const float* ap = A + (size_t)(bm + srow) * D_MODEL + scol;
    const unsigned short* whp = Wh + (size_t)(bn + srow) * D_MODEL + scol;
    const unsigned short* wlp = Wl + (size_t)(bn + srow) * D_MODEL + scol;

    for (int k0 = 0; k0 < D_MODEL; k0 += 64) {
        alignas(16) float fl[32];
        #pragma unroll
        for (int c = 0; c < 8; c++) *(float4*)&fl[4 * c] = *(const float4*)(ap + 4 * c);
        uint4 w0 = *(const uint4*)(whp + 0),  w1 = *(const uint4*)(whp + 8);
        uint4 w2 = *(const uint4*)(whp + 16), w3 = *(const uint4*)(whp + 24);
        uint4 x0, x1, x2, x3;
        if (split) {
            x0 = *(const uint4*)(wlp + 0);  x1 = *(const uint4*)(wlp + 8);
            x2 = *(const uint4*)(wlp + 16); x3 = *(const uint4*)(wlp + 24);
        }
        ap += 64; whp += 64; wlp += 64;

        unsigned int hw[16], lw[16];
        #pragma unroll
        for (int c = 0; c < 16; c++) {
            unsigned short h0 = f2bf(fl[2 * c]), h1 = f2bf(fl[2 * c + 1]);
            hw[c] = (unsigned int)h0 | ((unsigned int)h1 << 16);
            if (split) {
                unsigned short l0 = f2bf(fl[2 * c] - bf2f(h0));
                unsigned short l1 = f2bf(fl[2 * c + 1] - bf2f(h1));
                lw[c] = (unsigned int)l0 | ((unsigned int)l1 << 16);
            }
        }

        __syncthreads();
        unsigned int* ah = (unsigned int*)&Ah[srow * GLDK + scol];
        #pragma unroll
        for (int g = 0; g < 4; g++)
            *(uint4*)(ah + 4 * g) = make_uint4(hw[4 * g], hw[4 * g + 1], hw[4 * g + 2], hw[4 * g + 3]);
        if (split) {
            unsigned int* al = (unsigned int*)&Al[srow * GLDK + scol];
            #pragma unroll
            for (int g = 0; g < 4; g++)
                *(uint4*)(al + 4 * g) = make_uint4(lw[4 * g], lw[4 * g + 1], lw[4 * g + 2], lw[4 * g + 3]);
        }
        unsigned short* ws = &Whs[srow * GLDK + scol];
        *(uint4*)(ws + 0) = w0; *(uint4*)(ws + 8)  = w1;
        *(uint4*)(ws + 16) = w2; *(uint4*)(ws + 24) = w3;
        if (split) {
            unsigned short* wl2 = &Wls[srow * GLDK + scol];
            *(uint4*)(wl2 + 0) = x0; *(uint4*)(wl2 + 8)  = x1;
            *(uint4*)(wl2 + 16) = x2; *(uint4*)(wl2 + 24) = x3;
        }
        __syncthreads();

        #pragma unroll
        for (int kc = 0; kc < 64; kc += 32) {
            bh8 ahf[4], whf[4];
            #pragma unroll
            for (int i = 0; i < 4; i++)
                ahf[i] = *(bh8*)&Ah[(wm + i * 16 + l15) * GLDK + kc + q4 * 8];
            #pragma unroll
            for (int j = 0; j < 4; j++)
                whf[j] = *(bh8*)&Whs[(wn + j * 16 + l15) * GLDK + kc + q4 * 8];
            #pragma unroll
            for (int i = 0; i < 4; i++)
                #pragma unroll
                for (int j = 0; j < 4; j++)
                    acc[i][j] = __builtin_amdgcn_mfma_f32_16x16x32_bf16(ahf[i], whf[j], acc[i][j], 0, 0, 0);
            if (split) {
                bh8 alf[4], wlf[4];
                #pragma unroll
                for (int i = 0; i < 4; i++)
                    alf[i] = *(bh8*)&Al[(wm + i * 16 + l15) * GLDK + kc + q4 * 8];
                #pragma unroll
                for (int j = 0; j < 4; j++)
                    wlf[j] = *(bh8*)&Wls[(wn + j * 16 + l15) * GLDK + kc + q4 * 8];
                #pragma unroll
                for (int i = 0; i < 4; i++)
                    #pragma unroll
                    for (int j = 0; j < 4; j++) {
                        acc[i][j] = __builtin_amdgcn_mfma_f32_16x16x32_bf16(ahf[i], wlf[j], acc[i][j], 0, 0, 0);
                        acc[i][j] = __builtin_amdgcn_mfma_f32_16x16x32_bf16(alf[i], whf[j], acc[i][j], 0, 0, 0);
                    }
            }
        }
    }

    if (split) {
        // fused k RMS-norm: row's 64 cols = (j,l15) within this wave;
        // reduce over the 16 l15 lanes sharing q4.
        int hh = (bn + wn) >> 6;
        float bv[4];
        #pragma unroll
        for (int j = 0; j < 4; j++) bv[j] = Bi[bn + wn + j * 16 + l15];
        #pragma unroll
        for (int i = 0; i < 4; i++) {
            #pragma unroll
            for (int r = 0; r < 4; r++) {
                int row = bm + wm + i * 16 + q4 * 4 + r;
                int bb = row >> 10, tt = row & 1023;
                float vv[4]; float ss = 0.f;
                #pragma unroll
                for (int j = 0; j < 4; j++) {
                    vv[j] = acc[i][j][r] + bv[j];
                    ss += vv[j] * vv[j];
                }
                ss += __shfl_xor(ss, 1); ss += __shfl_xor(ss, 2);
                ss += __shfl_xor(ss, 4); ss += __shfl_xor(ss, 8);
                float rms = sqrtf(ss * (1.0f / 64.0f));
                unsigned short* kp = Yk + (((size_t)(bb * NHEAD + hh)) * T_SEQ + tt) * 128;
                #pragma unroll
                for (int j = 0; j < 4; j++) {
                    float xn = vv[j] / (rms + 1e-6f);
                    unsigned short hi = f2bf(xn);
                    unsigned short lo = f2bf(xn - bf2f(hi));
                    kp[j * 16 + l15]      = hi;
                    kp[64 + j * 16 + l15] = lo;
                }
            }
        }
    } else {
        #pragma unroll
        for (int j = 0; j < 4; j++) {
            int col = bn + wn + j * 16 + l15;
            int hh = col >> 6, dd = col & 63;
            float bvv = Bi[col];
            #pragma unroll
            for (int i = 0; i < 4; i++) {
                int row0 = bm + wm + i * 16 + q4 * 4;
                int bb = row0 >> 10, tt = row0 & 1023;
                uint2 u;
                u.x = (unsigned int)f2bf(acc[i][j][0] + bvv) | ((unsigned int)f2bf(acc[i][j][1] + bvv) << 16);
                u.y = (unsigned int)f2bf(acc[i][j][2] + bvv) | ((unsigned int)f2bf(acc[i][j][3] + bvv) << 16);
                *(uint2*)(Yv + ((size_t)(bb * NHEAD + hh) * HDIM + dd) * T_SEQ + tt) = u;
            }
        }
    }
}

// ---------------------------------------------------------------------------
// normq: RMS-norm + exact top-k (ballot binary search) on q only; rewrite
// IN PLACE as row-interleaved bf16 hi/lo (row r: 64 hi | 64 lo shorts).
// ---------------------------------------------------------------------------
__global__ void normq(float* __restrict__ Q)
{
    int tid  = threadIdx.x;
    int wid  = tid >> 6;
    int lane = tid & 63;
    long rid = (long)blockIdx.x * 4 + wid;   // [(b*16+h)*1024 + t]
    int h    = (int)((rid >> 10) & 15);

    float* p = Q + rid * HDIM;
    float x = p[lane];
    float ss = x * x;
    #pragma unroll
    for (int off = 32; off > 0; off >>= 1) ss += __shfl_xor(ss, off);
    float rms = sqrtf(ss * (1.0f / 64.0f));
    float xn = x / (rms + 1e-6f);

    unsigned int ai = __float_as_uint(fabsf(xn));
    unsigned int t = 0;
    int keep = KEEPC[h];
    #pragma unroll
    for (int bit = 30; bit >= 0; --bit) {
        unsigned int cand = t | (1u << bit);
        unsigned long long b = __ballot(ai >= cand);
        if (__popcll(b) >= keep) t = cand;
    }
    if (ai < t) xn = 0.f;   // keep iff |x| >= (keep-th largest)

    unsigned short hi = f2bf(xn);
    unsigned short lo = f2bf(xn - bf2f(hi));
    unsigned short* ps = (unsigned short*)p;
    ps[lane]      = hi;
    ps[64 + lane] = lo;
}

// ---------------------------------------------------------------------------
// MFMA flash attention, transposed S + cooperative LDS staging.
// 1-D grid 1024, XCD-swizzled (all qt of one (b,h) share blk%8).
// ---------------------------------------------------------------------------
#define KST 72

__global__ __launch_bounds__(256, 4) void attn_kernel(
    const unsigned short* __restrict__ Qsg,   // [row][128] = 64 hi | 64 lo
    const unsigned short* __restrict__ Ksg,   // same layout (norm-split)
    const unsigned short* __restrict__ Vtg,   // [(bh)*64+d][1024] bf16
    unsigned short* __restrict__ Ctx, double* __restrict__ He)
{
    __shared__ unsigned short Kh[64 * KST];
    __shared__ unsigned short Kl[64 * KST];
    __shared__ unsigned short Vt[64 * KST];
    __shared__ unsigned short Ps[4][16 * KST];

    int tid = threadIdx.x;
    int blk = blockIdx.x;
    int low = blk & 7, rest = blk >> 3;
    int qt  = 15 - (rest & 15);               // heavy blocks first
    int r2  = rest >> 4;
    int h   = (r2 & 1) * 8 + low;
    int b   = r2 >> 1;
    int bh = b * NHEAD + h;
    size_t rbase = (size_t)bh * T_SEQ;

    int wave = tid >> 6, lane = tid & 63;
    int l15 = lane & 15, rg = lane >> 4;
    int srow = tid >> 2;
    int scol = (tid & 3) * 16;

    int qrow = qt * 64 + wave * 16 + l15;

    bh8 qf[2][2];
    {
        const unsigned short* qp = Qsg + (rbase + qrow) * 128 + rg * 8;
        qf[0][0] = *(const bh8*)(qp);
        qf[0][1] = *(const bh8*)(qp + 32);
        qf[1][0] = *(const bh8*)(qp + 64);
        qf[1][1] = *(const bh8*)(qp + 96);
    }

    float m = -1e30f, l = 0.f, s2 = 0.f;
    f32x4 o[4];
    #pragma unroll
    for (int n = 0; n < 4; n++) o[n] = (f32x4)0.f;

    unsigned short* myPs = &Ps[wave][0];
    const unsigned short* vbase = Vtg + (size_t)bh * HDIM * T_SEQ;

    for (int kt = 0; kt <= qt; ++kt) {
        const unsigned short* krow = Ksg + (rbase + kt * 64 + srow) * 128;
        uint4 kh0 = *(const uint4*)(krow + scol);
        uint4 kh1 = *(const uint4*)(krow + scol + 8);
        uint4 kl0 = *(const uint4*)(krow + 64 + scol);
        uint4 kl1 = *(const uint4*)(krow + 64 + scol + 8);
        const unsigned short* vrow = vbase + (size_t)srow * T_SEQ + kt * 64 + scol;
        uint4 vv0 = *(const uint4*)(vrow);
        uint4 vv1 = *(const uint4*)(vrow + 8);

        __syncthreads();
        *(uint4*)&Kh[srow * KST + scol]     = kh0;
        *(uint4*)&Kh[srow * KST + scol + 8] = kh1;
        *(uint4*)&Kl[srow * KST + scol]     = kl0;
        *(uint4*)&Kl[srow * KST + scol + 8] = kl1;
        *(uint4*)&Vt[srow * KST + scol]     = vv0;
        *(uint4*)&Vt[srow * KST + scol + 8] = vv1;
        __syncthreads();

        f32x4 s[4];
        #pragma unroll
        for (int n = 0; n < 4; n++) s[n] = (f32x4)0.f;
        #pragma unroll
        for (int n = 0; n < 4; n++) {
            const unsigned short* kr = &Kh[(n * 16 + l15) * KST + rg * 8];
            const unsigned short* lr = &Kl[(n * 16 + l15) * KST + rg * 8];
            bh8 ah0 = *(const bh8*)(kr);
            bh8 ah1 = *(const bh8*)(kr + 32);
            bh8 al0 = *(const bh8*)(lr);
            bh8 al1 = *(const bh8*)(lr + 32);
            s[n] = __builtin_amdgcn_mfma_f32_16x16x32_bf16(ah0, qf[0][0], s[n], 0, 0, 0);
            s[n] = __builtin_amdgcn_mfma_f32_16x16x32_bf16(ah1, qf[0][1], s[n], 0, 0, 0);
            s[n] = __builtin_amdgcn_mfma_f32_16x16x32_bf16(ah0, qf[1][0], s[n], 0, 0, 0);
            s[n] = __builtin_amdgcn_mfma_f32_16x16x32_bf16(ah1, qf[1][1], s[n], 0, 0, 0);
            s[n] = __builtin_amdgcn_mfma_f32_16x16x32_bf16(al0, qf[0][0], s[n], 0, 0, 0);
            s[n] = __builtin_amdgcn_mfma_f32_16x16x32_bf16(al1, qf[0][1], s[n], 0, 0, 0);
        }

        if (kt == qt) {
            #pragma unroll
            for (int n = 0; n < 4; n++)
                #pragma unroll
                for (int e = 0; e < 4; e++)
                    if (n * 16 + rg * 4 + e > wave * 16 + l15) s[n][e] = -1e30f;
        }

        float mx = -1e30f;
        #pragma unroll
        for (int n = 0; n < 4; n++)
            #pragma unroll
            for (int e = 0; e < 4; e++) mx = fmaxf(mx, s[n][e]);
        mx = fmaxf(mx, __shfl_xor(mx, 16));
        mx = fmaxf(mx, __shfl_xor(mx, 32));
        float mn = fmaxf(m, mx);
        float alpha = __expf(m - mn);
        m = mn;
        float rs = 0.f, rs2 = 0.f;
        #pragma unroll
        for (int n = 0; n < 4; n++)
            #pragma unroll
            for (int e = 0; e < 4; e++) {
                float pv = __expf(s[n][e] - mn);
                s[n][e] = pv;
                rs += pv; rs2 += pv * pv;
            }
        rs  += __shfl_xor(rs, 16);  rs  += __shfl_xor(rs, 32);
        rs2 += __shfl_xor(rs2, 16); rs2 += __shfl_xor(rs2, 32);
        l  = l * alpha + rs;
        s2 = s2 * alpha * alpha + rs2;

        #pragma unroll
        for (int n = 0; n < 4; n++) {
            uint2 u;
            u.x = (unsigned int)f2bf(s[n][0]) | ((unsigned int)f2bf(s[n][1]) << 16);
            u.y = (unsigned int)f2bf(s[n][2]) | ((unsigned int)f2bf(s[n][3]) << 16);
            *(uint2*)&myPs[l15 * KST + n * 16 + rg * 4] = u;
        }
        bh8 pf0 = *(bh8*)&myPs[l15 * KST + rg * 8];
        bh8 pf1 = *(bh8*)&myPs[l15 * KST + 32 + rg * 8];

        #pragma unroll
        for (int n = 0; n < 4; n++) {
            o[n] *= alpha;
            const unsigned short* vr = &Vt[(n * 16 + l15) * KST + rg * 8];
            bh8 v0 = *(const bh8*)(vr);
            bh8 v1 = *(const bh8*)(vr + 32);
            o[n] = __builtin_amdgcn_mfma_f32_16x16x32_bf16(v0, pf0, o[n], 0, 0, 0);
            o[n] = __builtin_amdgcn_mfma_f32_16x16x32_bf16(v1, pf1, o[n], 0, 0, 0);
        }
    }

    float linv = 1.f / l;
    float en = (rg == 0) ? s2 * linv * linv : 0.f;
    en += __shfl_xor(en, 1); en += __shfl_xor(en, 2);
    en += __shfl_xor(en, 4); en += __shfl_xor(en, 8);
    if (lane == 0) atomicAdd(&He[bh], (double)en);

    unsigned short* cp = Ctx + ((size_t)b * T_SEQ + qrow) * D_MODEL + h * HDIM;
    #pragma unroll
    for (int n = 0; n < 4; n++) {
        uint2 u;
        u.x = (unsigned int)f2bf(o[n][0] * linv) | ((unsigned int)f2bf(o[n][1] * linv) << 16);
        u.y = (unsigned int)f2bf(o[n][2] * linv) | ((unsigned int)f2bf(o[n][3] * linv) << 16);
        *(uint2*)(cp + n * 16 + rg * 4) = u;
    }
}

// ---------------------------------------------------------------------------
// Out-projection with FUSED head selection: every block recomputes the
// per-batch mask from He (identical f64 math/order as the old headsel).
// ---------------------------------------------------------------------------
__global__ __launch_bounds__(256, 2) void gemm_obf(
    const unsigned short* __restrict__ A, const unsigned short* __restrict__ W,
    const float* __restrict__ Bi, float* __restrict__ Y,
    const double* __restrict__ He)
{
    __shared__ unsigned short As[128 * GLDK];
    __shared__ unsigned short Ws[128 * GLDK];
    __shared__ double hs[34];       // [0..15] e, [16..31] p/terms, [32] sum
    __shared__ float maskS[NHEAD];

    int tid  = threadIdx.x;
    int blk  = blockIdx.x;
    int low  = blk & 7, rest = blk >> 3;
    int bn   = (rest & 7) * 128;
    int bm   = (((rest >> 3) << 3) + low) * 128;
    int batch = bm >> 10;

    // ---- fused headsel (per-block, deterministic)
    if (tid < NHEAD) hs[tid] = He[batch * NHEAD + tid] * (1.0 / (1024.0 * 1024.0));
    __syncthreads();
    if (tid < NHEAD) {
        double mx = hs[0];
        for (int h2 = 1; h2 < NHEAD; h2++) mx = fmax(mx, hs[h2]);
        hs[NHEAD + tid] = exp(hs[tid] - mx);
    }
    __syncthreads();
    if (tid == 0) {
        double s = 0.0;
        for (int h2 = 0; h2 < NHEAD; h2++) s += hs[NHEAD + h2];
        hs[32] = s;
    }
    __syncthreads();
    if (tid < NHEAD) {
        double ph = hs[NHEAD + tid] / hs[32];
        hs[NHEAD + tid] = ph * log(ph + 1e-9);
    }
    __syncthreads();
    if (tid == 0) {
        double ent = 0.0;
        for (int h2 = 0; h2 < NHEAD; h2++) ent -= hs[NHEAD + h2];
        double entn = ent / log(16.0);
        entn = fmin(fmax(entn, 0.0), 1.0);
        int keep = (int)rint(2.0 + entn * 4.0);
        if (keep < 1) keep = 1;
        if (keep > NHEAD) keep = NHEAD;
        double srt[NHEAD];
        for (int h2 = 0; h2 < NHEAD; h2++) srt[h2] = hs[h2];
        for (int i = 1; i < NHEAD; i++) {
            double v = srt[i]; int j = i - 1;
            while (j >= 0 && srt[j] < v) { srt[j + 1] = srt[j]; j--; }
            srt[j + 1] = v;
        }
        double th = srt[keep - 1];
        for (int h2 = 0; h2 < NHEAD; h2++)
            maskS[h2] = (hs[h2] >= th) ? 1.0f : 0.0f;
    }
    __syncthreads();

    int wave = tid >> 6, lane = tid & 63;
    int l15  = lane & 15, q4 = lane >> 4;
    int wm   = (wave >> 1) * 64, wn = (wave & 1) * 64;
    int srow = tid >> 1;
    int scol = (tid & 1) * 32;

    f32x4 acc[4][4];
    #pragma unroll
    for (int i = 0; i < 4; i++)
        #pragma unroll
        for (int j = 0; j < 4; j++) acc[i][j] = (f32x4)0.f;

    const unsigned short* ap = A + (size_t)(bm + srow) * D_MODEL + scol;
    const unsigned short* wp = W + (size_t)(bn + srow) * D_MODEL + scol;

    for (int k0 = 0; k0 < D_MODEL; k0 += 64) {
        uint4 a0 = *(const uint4*)(ap + 0),  a1 = *(const uint4*)(ap + 8);
        uint4 a2 = *(const uint4*)(ap + 16), a3 = *(const uint4*)(ap + 24);
        uint4 w0 = *(const uint4*)(wp + 0),  w1 = *(const uint4*)(wp + 8);
        uint4 w2 = *(const uint4*)(wp + 16), w3 = *(const uint4*)(wp + 24);
        ap += 64; wp += 64;
        if (maskS[k0 >> 6] == 0.f) {
            a0 = a1 = a2 = a3 = make_uint4(0, 0, 0, 0);
        }
        __syncthreads();
        unsigned short* as = &As[srow * GLDK + scol];
        *(uint4*)(as + 0) = a0; *(uint4*)(as + 8)  = a1;
        *(uint4*)(as + 16) = a2; *(uint4*)(as + 24) = a3;
        unsigned short* ws = &Ws[srow * GLDK + scol];
        *(uint4*)(ws + 0) = w0; *(uint4*)(ws + 8)  = w1;
        *(uint4*)(ws + 16) = w2; *(uint4*)(ws + 24) = w3;
        __syncthreads();

        #pragma unroll
        for (int kc = 0; kc < 64; kc += 32) {
            bh8 af[4], wf[4];
            #pragma unroll
            for (int i = 0; i < 4; i++)
                af[i] = *(bh8*)&As[(wm + i * 16 + l15) * GLDK + kc + q4 * 8];
            #pragma unroll
            for (int j = 0; j < 4; j++)
                wf[j] = *(bh8*)&Ws[(wn + j * 16 + l15) * GLDK + kc + q4 * 8];
            #pragma unroll
            for (int i = 0; i < 4; i++)
                #pragma unroll
                for (int j = 0; j < 4; j++)
                    acc[i][j] = __builtin_amdgcn_mfma_f32_16x16x32_bf16(af[i], wf[j], acc[i][j], 0, 0, 0);
        }
    }

    #pragma unroll
    for (int j = 0; j < 4; j++) {
        int col = bn + wn + j * 16 + l15;
        float bv = Bi[col];
        #pragma unroll
        for (int i = 0; i < 4; i++) {
            int row = bm + wm + i * 16 + q4 * 4;
            #pragma unroll
            for (int r = 0; r < 4; r++)
                Y[(size_t)(row + r) * D_MODEL + col] = acc[i][j][r] + bv;
        }
    }
}

// ---------------------------------------------------------------------------
extern "C" void kernel_launch(void* const* d_in, const int* in_sizes, int n_in,
                              void* d_out, int out_size, void* d_ws, size_t ws_size,
                              hipStream_t stream)
{
    (void)in_sizes; (void)n_in; (void)out_size; (void)ws_size;
    const float* x  = (const float*)d_in[0];
    const float* qw = (const float*)d_in[1];
    const float* qb = (const float*)d_in[2];
    const float* kw = (const float*)d_in[3];
    const float* kb = (const float*)d_in[4];
    const float* vw = (const float*)d_in[5];
    const float* vb = (const float*)d_in[6];
    const float* ow = (const float*)d_in[7];
    const float* ob = (const float*)d_in[8];
    float* out = (float*)d_out;

    // Memory map (fix for round 9's 8-vs-16 MB kbf bug):
    //   0-16   q_hm (fp32, rewritten in place as bf16 hi/lo by normq)
    //  16-32   kbf  (norm-split bf16: 65536 rows x 256 B = 16 MB)
    //  32-40   vt   (V^T bf16, 8 MB)
    //  40-48   ctxb (bf16, 8 MB)
    //  32-48   dig  (16 MB, OVERLAYS vt+ctxb; fully consumed by gemm_q_i8
    //               before gemm_kv writes vt / attn writes ctxb)
    //  48-56   kwh, kwl, vwb, owb (2 MB each)
    //  56-57   sg
    //  57+     he (512 B)
    char* base = (char*)d_ws;
    const size_t MB = (size_t)1024 * 1024;
    float*          q_hm = (float*)(base);
    unsigned short* kbf  = (unsigned short*)(base + 16 * MB);
    unsigned short* vt   = (unsigned short*)(base + 32 * MB);
    unsigned short* ctxb = (unsigned short*)(base + 40 * MB);
    signed char*    dig  = (signed char*)(base + 32 * MB);
    unsigned short* kwh  = (unsigned short*)(base + 48 * MB);
    unsigned short* kwl  = (unsigned short*)(base + 50 * MB);
    unsigned short* vwb  = (unsigned short*)(base + 52 * MB);
    unsigned short* owb  = (unsigned short*)(base + 54 * MB);
    signed char*    sg   = (signed char*)(base + 56 * MB);
    double*         he   = (double*)(base + 57 * MB);

    hipMemsetAsync(he, 0, 64 * sizeof(double), stream);

    // all weight casts + x digitize + qw sign in one pass
    cast_prep<<<4096, 256, 0, stream>>>(kw, kwh, kwl, vw, vwb, ow, owb,
                                        x, dig, qw, sg);
    // q projection (exact i8 digits) — consumes dig before kv overwrites vt
    gemm_q_i8<<<1024, 256, 0, stream>>>(dig, sg, qb, q_hm);
    // k (split-bf16 + fused RMS-norm -> kbf) and v (bf16 -> V^T) together
    gemm_kv<<<512, 256, 0, stream>>>(x, kwh, kwl, kb, vwb, vb, kbf, vt);
    // q: norm + exact top-k, rewrite in place as bf16 hi/lo
    normq<<<16384, 256, 0, stream>>>(q_hm);
    attn_kernel<<<1024, 256, 0, stream>>>(
        (const unsigned short*)q_hm, kbf, vt, ctxb, he);
    // out-projection with fused head selection
    gemm_obf<<<256, 256, 0, stream>>>(ctxb, owb, ob, out, he);
}